// Round 9
// baseline (1466.997 us; speedup 1.0000x reference)
//
#include <hip/hip_runtime.h>
#include <stdint.h>

typedef __attribute__((ext_vector_type(4))) float f32x4;
typedef __attribute__((ext_vector_type(8))) short bf16x8;

#define HIDC 256
#define MSGC 128
#define NLAYER 10

__device__ __forceinline__ ushort f2bf(float f) {
  union { float f; uint32_t u; } a; a.f = f;
  uint32_t u = a.u;
  return (ushort)((u + 0x7fffu + ((u >> 16) & 1u)) >> 16);
}
__device__ __forceinline__ float bf2f(ushort h) {
  union { float f; uint32_t u; } a; a.u = ((uint32_t)h) << 16;
  return a.f;
}

// ---------------------------------------------------------------------------
// W1 GEMM: A bf16 [M x 256], B bf16 [128 x 256](transposed), C bf16 [M x 128].
// Tile 128x128, 4 waves, BK=64, RELU fused.
// ---------------------------------------------------------------------------
__global__ __launch_bounds__(256, 4) void gemm_w1(
    const ushort* __restrict__ A, const ushort* __restrict__ B,
    const float* __restrict__ bias, ushort* __restrict__ C, int M) {
  __shared__ ushort lA[128 * 64];
  __shared__ ushort lB[128 * 64];
  const int tid = threadIdx.x;
  const int m0 = blockIdx.x * 128;
  const int lane = tid & 63;
  const int w = tid >> 6;
  const int wm = (w >> 1) * 64;
  const int wn = (w & 1) * 64;
  const int rr = tid >> 3;  // 0..31
  const int cc = tid & 7;   // 0..7
  f32x4 acc[4][4] = {};

#pragma unroll
  for (int s = 0; s < 4; ++s) {  // K = 256
    const int k0 = s * 64;
#pragma unroll
    for (int p = 0; p < 4; ++p) {
      const int row = p * 32 + rr;
      const int gm = m0 + row;
      bf16x8 av = {0, 0, 0, 0, 0, 0, 0, 0};
      if (gm < M) av = *(const bf16x8*)(A + (size_t)gm * 256 + k0 + cc * 8);
      const uint32_t off = (uint32_t)((row * 128 + cc * 16) ^ ((row & 7) << 4));
      *(bf16x8*)((char*)lA + off) = av;
    }
#pragma unroll
    for (int p = 0; p < 4; ++p) {
      const int row = p * 32 + rr;
      bf16x8 bv = *(const bf16x8*)(B + (size_t)row * 256 + k0 + cc * 8);
      const uint32_t off = (uint32_t)((row * 128 + cc * 16) ^ ((row & 7) << 4));
      *(bf16x8*)((char*)lB + off) = bv;
    }
    __syncthreads();
#pragma unroll
    for (int kk = 0; kk < 2; ++kk) {
      bf16x8 ah[4];
#pragma unroll
      for (int i = 0; i < 4; ++i) {
        const int arow = wm + i * 16 + (lane & 15);
        const uint32_t ao =
            (uint32_t)((arow * 128 + kk * 64 + ((lane >> 4) * 16)) ^ ((arow & 7) << 4));
        ah[i] = *(const bf16x8*)((const char*)lA + ao);
      }
#pragma unroll
      for (int j = 0; j < 4; ++j) {
        const int brow = wn + j * 16 + (lane & 15);
        const uint32_t bo =
            (uint32_t)((brow * 128 + kk * 64 + ((lane >> 4) * 16)) ^ ((brow & 7) << 4));
        const bf16x8 bv = *(const bf16x8*)((const char*)lB + bo);
#pragma unroll
        for (int i = 0; i < 4; ++i)
          acc[i][j] = __builtin_amdgcn_mfma_f32_16x16x32_bf16(ah[i], bv, acc[i][j], 0, 0, 0);
      }
    }
    __syncthreads();
  }
  float bi[4];
#pragma unroll
  for (int j = 0; j < 4; ++j) bi[j] = bias[wn + j * 16 + (lane & 15)];
#pragma unroll
  for (int i = 0; i < 4; ++i) {
    const int gm0 = m0 + wm + i * 16 + ((lane >> 4) << 2);
#pragma unroll
    for (int r = 0; r < 4; ++r) {
      const int gm = gm0 + r;
      if (gm < M) {
        const size_t base = (size_t)gm * 128 + wn + (lane & 15);
#pragma unroll
        for (int j = 0; j < 4; ++j)
          C[base + j * 16] = f2bf(fmaxf(acc[i][j][r] + bi[j], 0.f));
      }
    }
  }
}

// ---------------------------------------------------------------------------
// Win GEMM (z0): A bf16 [M x 128], B bf16 [256 x 128], C bf16 [M x 256].
// Tile 128x256, 8 waves, BK=64.
// ---------------------------------------------------------------------------
__global__ __launch_bounds__(512, 4) void gemm_win(
    const ushort* __restrict__ A, const ushort* __restrict__ B,
    const float* __restrict__ bias, ushort* __restrict__ C, int M) {
  __shared__ ushort lA[128 * 64];
  __shared__ ushort lB[256 * 64];
  const int tid = threadIdx.x;
  const int m0 = blockIdx.x * 128;
  const int lane = tid & 63;
  const int w = tid >> 6;
  const int wm = (w >> 2) * 64;
  const int wn = (w & 3) * 64;
  const int rr = tid >> 3;
  const int cc = tid & 7;
  f32x4 acc[4][4] = {};
  const int K = 128;

#pragma unroll
  for (int s = 0; s < 2; ++s) {
    const int k0 = s * 64;
#pragma unroll
    for (int p = 0; p < 2; ++p) {
      const int row = p * 64 + rr;
      const int gm = m0 + row;
      bf16x8 av = {0, 0, 0, 0, 0, 0, 0, 0};
      if (gm < M) av = *(const bf16x8*)(A + (size_t)gm * K + k0 + cc * 8);
      const uint32_t off = (uint32_t)((row * 128 + cc * 16) ^ ((row & 7) << 4));
      *(bf16x8*)((char*)lA + off) = av;
    }
#pragma unroll
    for (int p = 0; p < 4; ++p) {
      const int row = p * 64 + rr;
      bf16x8 bv = *(const bf16x8*)(B + (size_t)row * K + k0 + cc * 8);
      const uint32_t off = (uint32_t)((row * 128 + cc * 16) ^ ((row & 7) << 4));
      *(bf16x8*)((char*)lB + off) = bv;
    }
    __syncthreads();
#pragma unroll
    for (int kk = 0; kk < 2; ++kk) {
      bf16x8 ah[4];
#pragma unroll
      for (int i = 0; i < 4; ++i) {
        const int arow = wm + i * 16 + (lane & 15);
        const uint32_t ao =
            (uint32_t)((arow * 128 + kk * 64 + ((lane >> 4) * 16)) ^ ((arow & 7) << 4));
        ah[i] = *(const bf16x8*)((const char*)lA + ao);
      }
#pragma unroll
      for (int j = 0; j < 4; ++j) {
        const int brow = wn + j * 16 + (lane & 15);
        const uint32_t bo =
            (uint32_t)((brow * 128 + kk * 64 + ((lane >> 4) * 16)) ^ ((brow & 7) << 4));
        const bf16x8 bv = *(const bf16x8*)((const char*)lB + bo);
#pragma unroll
        for (int i = 0; i < 4; ++i)
          acc[i][j] = __builtin_amdgcn_mfma_f32_16x16x32_bf16(ah[i], bv, acc[i][j], 0, 0, 0);
      }
    }
    __syncthreads();
  }
  float bi[4];
#pragma unroll
  for (int j = 0; j < 4; ++j) bi[j] = bias[wn + j * 16 + (lane & 15)];
#pragma unroll
  for (int i = 0; i < 4; ++i) {
    const int gm0 = m0 + wm + i * 16 + ((lane >> 4) << 2);
#pragma unroll
    for (int r = 0; r < 4; ++r) {
      const int gm = gm0 + r;
      if (gm < M) {
        const size_t base = (size_t)gm * 256 + wn + (lane & 15);
#pragma unroll
        for (int j = 0; j < 4; ++j)
          C[base + j * 16] = f2bf(acc[i][j][r] + bi[j]);
      }
    }
  }
}

// ---------------------------------------------------------------------------
// Fused layer tail: z' = LN( relu( (s@W2+b2+z) @ U1 + c1 ) @ U2 + c2 )*g + b_
// Tile 64x256, 8 waves, h/O live in LDS only. 74 KB LDS -> 2 blocks/CU.
// ---------------------------------------------------------------------------
__global__ __launch_bounds__(512, 4) void layer_fused(
    const ushort* __restrict__ s128, const ushort* __restrict__ z,
    const ushort* __restrict__ W2T, const float* __restrict__ b2,
    const ushort* __restrict__ U1T, const float* __restrict__ c1,
    const ushort* __restrict__ U2T, const float* __restrict__ c2,
    const float* __restrict__ g, const float* __restrict__ b_,
    ushort* __restrict__ zout, int M) {
  __shared__ ushort lA[64 * 64];     // 8 KB  (s tile)
  __shared__ ushort lB[256 * 64];    // 32 KB (weight chunk)
  __shared__ ushort hO[64 * 256];    // 32 KB (h, then O)
  __shared__ float sstat[2][4][64];  // 2 KB
  const int tid = threadIdx.x;
  const int m0 = blockIdx.x * 64;
  const int lane = tid & 63;
  const int w = tid >> 6;        // 0..7
  const int wm = (w >> 2) * 32;  // 0,32
  const int wn = (w & 3) * 64;   // 0,64,128,192
  const int rr = tid >> 3;       // 0..63
  const int cc = tid & 7;        // 0..7
  f32x4 acc[2][4];

  // ---------------- phase 0: h = s @ W2^T + b2 + z  (K=128) ----------------
#pragma unroll
  for (int i = 0; i < 2; ++i)
#pragma unroll
    for (int j = 0; j < 4; ++j) acc[i][j] = (f32x4){0.f, 0.f, 0.f, 0.f};
#pragma unroll
  for (int s = 0; s < 2; ++s) {
    const int k0 = s * 64;
    {
      const int gm = m0 + rr;
      bf16x8 av = {0, 0, 0, 0, 0, 0, 0, 0};
      if (gm < M) av = *(const bf16x8*)(s128 + (size_t)gm * 128 + k0 + cc * 8);
      const uint32_t off = (uint32_t)((rr * 128 + cc * 16) ^ ((rr & 7) << 4));
      *(bf16x8*)((char*)lA + off) = av;
    }
#pragma unroll
    for (int p = 0; p < 4; ++p) {
      const int row = p * 64 + rr;
      bf16x8 bv = *(const bf16x8*)(W2T + (size_t)row * 128 + k0 + cc * 8);
      const uint32_t off = (uint32_t)((row * 128 + cc * 16) ^ ((row & 7) << 4));
      *(bf16x8*)((char*)lB + off) = bv;
    }
    __syncthreads();
#pragma unroll
    for (int kk = 0; kk < 2; ++kk) {
      bf16x8 ah[2];
#pragma unroll
      for (int i = 0; i < 2; ++i) {
        const int arow = wm + i * 16 + (lane & 15);
        const uint32_t ao =
            (uint32_t)((arow * 128 + kk * 64 + ((lane >> 4) * 16)) ^ ((arow & 7) << 4));
        ah[i] = *(const bf16x8*)((const char*)lA + ao);
      }
#pragma unroll
      for (int j = 0; j < 4; ++j) {
        const int brow = wn + j * 16 + (lane & 15);
        const uint32_t bo =
            (uint32_t)((brow * 128 + kk * 64 + ((lane >> 4) * 16)) ^ ((brow & 7) << 4));
        const bf16x8 bv = *(const bf16x8*)((const char*)lB + bo);
#pragma unroll
        for (int i = 0; i < 2; ++i)
          acc[i][j] = __builtin_amdgcn_mfma_f32_16x16x32_bf16(ah[i], bv, acc[i][j], 0, 0, 0);
      }
    }
    __syncthreads();
  }
  {
    float bi[4];
#pragma unroll
    for (int j = 0; j < 4; ++j) bi[j] = b2[wn + j * 16 + (lane & 15)];
#pragma unroll
    for (int i = 0; i < 2; ++i) {
#pragma unroll
      for (int r = 0; r < 4; ++r) {
        const int rl = wm + i * 16 + ((lane >> 4) << 2) + r;
        const int gm = m0 + rl;
#pragma unroll
        for (int j = 0; j < 4; ++j) {
          const int col = wn + j * 16 + (lane & 15);
          float v = acc[i][j][r] + bi[j];
          if (gm < M) v += bf2f(z[(size_t)gm * 256 + col]);
          const uint32_t off = (uint32_t)((rl * 512 + col * 2) ^ ((rl & 7) << 4));
          *(ushort*)((char*)hO + off) = f2bf(v);
        }
      }
    }
  }
  __syncthreads();

  // ---------------- phase 1: O = relu(h @ U1^T + c1)  (K=256) ----------------
#pragma unroll
  for (int i = 0; i < 2; ++i)
#pragma unroll
    for (int j = 0; j < 4; ++j) acc[i][j] = (f32x4){0.f, 0.f, 0.f, 0.f};
#pragma unroll
  for (int s = 0; s < 4; ++s) {
    const int k0 = s * 64;
#pragma unroll
    for (int p = 0; p < 4; ++p) {
      const int row = p * 64 + rr;
      bf16x8 bv = *(const bf16x8*)(U1T + (size_t)row * 256 + k0 + cc * 8);
      const uint32_t off = (uint32_t)((row * 128 + cc * 16) ^ ((row & 7) << 4));
      *(bf16x8*)((char*)lB + off) = bv;
    }
    __syncthreads();
#pragma unroll
    for (int kk = 0; kk < 2; ++kk) {
      bf16x8 ah[2];
#pragma unroll
      for (int i = 0; i < 2; ++i) {
        const int arow = wm + i * 16 + (lane & 15);
        const uint32_t ao =
            (uint32_t)((arow * 512 + k0 * 2 + kk * 64 + ((lane >> 4) * 16)) ^ ((arow & 7) << 4));
        ah[i] = *(const bf16x8*)((const char*)hO + ao);
      }
#pragma unroll
      for (int j = 0; j < 4; ++j) {
        const int brow = wn + j * 16 + (lane & 15);
        const uint32_t bo =
            (uint32_t)((brow * 128 + kk * 64 + ((lane >> 4) * 16)) ^ ((brow & 7) << 4));
        const bf16x8 bv = *(const bf16x8*)((const char*)lB + bo);
#pragma unroll
        for (int i = 0; i < 2; ++i)
          acc[i][j] = __builtin_amdgcn_mfma_f32_16x16x32_bf16(ah[i], bv, acc[i][j], 0, 0, 0);
      }
    }
    __syncthreads();
  }
  {
    float bi[4];
#pragma unroll
    for (int j = 0; j < 4; ++j) bi[j] = c1[wn + j * 16 + (lane & 15)];
#pragma unroll
    for (int i = 0; i < 2; ++i) {
#pragma unroll
      for (int r = 0; r < 4; ++r) {
        const int rl = wm + i * 16 + ((lane >> 4) << 2) + r;
#pragma unroll
        for (int j = 0; j < 4; ++j) {
          const int col = wn + j * 16 + (lane & 15);
          const float v = fmaxf(acc[i][j][r] + bi[j], 0.f);
          const uint32_t off = (uint32_t)((rl * 512 + col * 2) ^ ((rl & 7) << 4));
          *(ushort*)((char*)hO + off) = f2bf(v);
        }
      }
    }
  }
  __syncthreads();

  // ---------------- phase 2: y = LN(O @ U2^T + c2)*g + b_  (K=256) ----------
#pragma unroll
  for (int i = 0; i < 2; ++i)
#pragma unroll
    for (int j = 0; j < 4; ++j) acc[i][j] = (f32x4){0.f, 0.f, 0.f, 0.f};
#pragma unroll
  for (int s = 0; s < 4; ++s) {
    const int k0 = s * 64;
#pragma unroll
    for (int p = 0; p < 4; ++p) {
      const int row = p * 64 + rr;
      bf16x8 bv = *(const bf16x8*)(U2T + (size_t)row * 256 + k0 + cc * 8);
      const uint32_t off = (uint32_t)((row * 128 + cc * 16) ^ ((row & 7) << 4));
      *(bf16x8*)((char*)lB + off) = bv;
    }
    __syncthreads();
#pragma unroll
    for (int kk = 0; kk < 2; ++kk) {
      bf16x8 ah[2];
#pragma unroll
      for (int i = 0; i < 2; ++i) {
        const int arow = wm + i * 16 + (lane & 15);
        const uint32_t ao =
            (uint32_t)((arow * 512 + k0 * 2 + kk * 64 + ((lane >> 4) * 16)) ^ ((arow & 7) << 4));
        ah[i] = *(const bf16x8*)((const char*)hO + ao);
      }
#pragma unroll
      for (int j = 0; j < 4; ++j) {
        const int brow = wn + j * 16 + (lane & 15);
        const uint32_t bo =
            (uint32_t)((brow * 128 + kk * 64 + ((lane >> 4) * 16)) ^ ((brow & 7) << 4));
        const bf16x8 bv = *(const bf16x8*)((const char*)lB + bo);
#pragma unroll
        for (int i = 0; i < 2; ++i)
          acc[i][j] = __builtin_amdgcn_mfma_f32_16x16x32_bf16(ah[i], bv, acc[i][j], 0, 0, 0);
      }
    }
    __syncthreads();
  }
  // LN epilogue
  {
    float bi[4], gv[4], bv[4];
#pragma unroll
    for (int j = 0; j < 4; ++j) {
      const int col = wn + j * 16 + (lane & 15);
      bi[j] = c2[col];
      gv[j] = g[col];
      bv[j] = b_[col];
    }
#pragma unroll
    for (int i = 0; i < 2; ++i) {
#pragma unroll
      for (int r = 0; r < 4; ++r) {
        float s1 = 0.f, s2 = 0.f;
#pragma unroll
        for (int j = 0; j < 4; ++j) {
          float v = acc[i][j][r] + bi[j];
          acc[i][j][r] = v;
          s1 += v;
          s2 += v * v;
        }
#pragma unroll
        for (int d = 1; d < 16; d <<= 1) {
          s1 += __shfl_xor(s1, d);
          s2 += __shfl_xor(s2, d);
        }
        if ((lane & 15) == 0) {
          const int rl = wm + i * 16 + ((lane >> 4) << 2) + r;
          sstat[0][w & 3][rl] = s1;
          sstat[1][w & 3][rl] = s2;
        }
      }
    }
    __syncthreads();
#pragma unroll
    for (int i = 0; i < 2; ++i) {
#pragma unroll
      for (int r = 0; r < 4; ++r) {
        const int rl = wm + i * 16 + ((lane >> 4) << 2) + r;
        const float s1 = sstat[0][0][rl] + sstat[0][1][rl] + sstat[0][2][rl] + sstat[0][3][rl];
        const float s2 = sstat[1][0][rl] + sstat[1][1][rl] + sstat[1][2][rl] + sstat[1][3][rl];
        const float mu = s1 * (1.f / 256.f);
        const float var = s2 * (1.f / 256.f) - mu * mu;
        const float rs = rsqrtf(var + 1e-5f);
        const int gm = m0 + rl;
        if (gm < M) {
          const size_t base = (size_t)gm * 256 + wn + (lane & 15);
#pragma unroll
          for (int j = 0; j < 4; ++j)
            zout[base + j * 16] = f2bf((acc[i][j][r] - mu) * rs * gv[j] + bv[j]);
        }
      }
    }
  }
}

// ---------------------------------------------------------------------------
// Fold: outp (+)= sum_{k<P} betas[l0+k] * bf2f(zbase[k][i]); 8 elems/thread.
// ---------------------------------------------------------------------------
template <int WRITE>
__global__ __launch_bounds__(256) void fold_kernel(
    const ushort* __restrict__ zbase, size_t ZS, const float* __restrict__ betas,
    int l0, int P, float* __restrict__ outp, int total8) {
  const int i = blockIdx.x * 256 + threadIdx.x;
  if (i >= total8) return;
  float a[8] = {};
  for (int k = 0; k < P; ++k) {
    const float bl = betas[l0 + k];
    const uint4 u = ((const uint4*)(zbase + k * ZS))[i];
    const uint32_t ww[4] = {u.x, u.y, u.z, u.w};
#pragma unroll
    for (int q = 0; q < 4; ++q) {
      union { uint32_t u; float f; } lo, hi;
      lo.u = ww[q] << 16;
      hi.u = ww[q] & 0xffff0000u;
      a[2 * q] += bl * lo.f;
      a[2 * q + 1] += bl * hi.f;
    }
  }
  f32x4 o0 = {a[0], a[1], a[2], a[3]};
  f32x4 o1 = {a[4], a[5], a[6], a[7]};
  if (WRITE) {
    ((f32x4*)outp)[(size_t)i * 2] = o0;
    ((f32x4*)outp)[(size_t)i * 2 + 1] = o1;
  } else {
    f32x4 p0 = ((f32x4*)outp)[(size_t)i * 2];
    f32x4 p1 = ((f32x4*)outp)[(size_t)i * 2 + 1];
    ((f32x4*)outp)[(size_t)i * 2] = p0 + o0;
    ((f32x4*)outp)[(size_t)i * 2 + 1] = p1 + o1;
  }
}

// ---------------------------------------------------------------------------
// CSR build (parallel scan), 4 edges/thread for atomic ILP
// ---------------------------------------------------------------------------
__global__ void count_kernel(const int* __restrict__ dstv, int* __restrict__ deg, int E) {
  const int i = (blockIdx.x * 256 + threadIdx.x) * 4;
#pragma unroll
  for (int k = 0; k < 4; ++k)
    if (i + k < E) atomicAdd(&deg[dstv[i + k]], 1);
}

__global__ void scanA_kernel(const int* __restrict__ deg, int* __restrict__ excl,
                             int* __restrict__ bsum, int n) {
  __shared__ int sm[256];
  const int i = blockIdx.x * 256 + threadIdx.x;
  const int v = (i < n) ? deg[i] : 0;
  sm[threadIdx.x] = v;
  __syncthreads();
  for (int off = 1; off < 256; off <<= 1) {
    int t = (threadIdx.x >= off) ? sm[threadIdx.x - off] : 0;
    __syncthreads();
    sm[threadIdx.x] += t;
    __syncthreads();
  }
  if (i < n) excl[i] = sm[threadIdx.x] - v;
  if (threadIdx.x == 255) bsum[blockIdx.x] = sm[255];
}

__global__ void scanB_kernel(const int* __restrict__ bsum, int* __restrict__ boff, int nb) {
  __shared__ int sm[256];
  const int v = (threadIdx.x < nb) ? bsum[threadIdx.x] : 0;
  sm[threadIdx.x] = v;
  __syncthreads();
  for (int off = 1; off < 256; off <<= 1) {
    int t = (threadIdx.x >= off) ? sm[threadIdx.x - off] : 0;
    __syncthreads();
    sm[threadIdx.x] += t;
    __syncthreads();
  }
  if (threadIdx.x < nb) boff[threadIdx.x] = sm[threadIdx.x] - v;
}

__global__ void scanC_kernel(const int* __restrict__ deg, const int* __restrict__ excl,
                             const int* __restrict__ boff, int* __restrict__ rowptr,
                             int* __restrict__ fillptr, float* __restrict__ invc,
                             int n, int E) {
  const int i = blockIdx.x * 256 + threadIdx.x;
  if (i < n) {
    const int r = excl[i] + boff[blockIdx.x];
    rowptr[i] = r;
    fillptr[i] = r;
    invc[i] = 1.0f / (float)(deg[i] + 1);
  }
  if (i == 0) rowptr[n] = E;
}

__global__ void fill_kernel(const int* __restrict__ srcv, const int* __restrict__ dstv,
                            int* __restrict__ fillptr, int* __restrict__ colv, int E) {
  const int i = (blockIdx.x * 256 + threadIdx.x) * 4;
#pragma unroll
  for (int k = 0; k < 4; ++k)
    if (i + k < E) {
      int p = atomicAdd(&fillptr[dstv[i + k]], 1);
      colv[p] = srcv[i + k];
    }
}

// ---------------------------------------------------------------------------
// 128-d aggregation, quarter-wave (16 lanes x 16B) per node, x4 unroll.
// ---------------------------------------------------------------------------
__global__ __launch_bounds__(256) void agg128_kernel(
    const ushort* __restrict__ T, const int* __restrict__ rowptr,
    const int* __restrict__ colv, const float* __restrict__ invc,
    ushort* __restrict__ sout, int n) {
  const int node = blockIdx.x * 16 + (threadIdx.x >> 4);
  if (node >= n) return;
  const int q = threadIdx.x & 15;
  const uint4* Tv = (const uint4*)T;  // row = 16 x 16B chunks
  float a[8] = {}, b[8] = {}, c[8] = {}, d[8] = {};
  auto addu = [](float* acc, uint4 u) {
    const uint32_t ww[4] = {u.x, u.y, u.z, u.w};
#pragma unroll
    for (int k = 0; k < 4; ++k) {
      union { uint32_t u; float f; } lo, hi;
      lo.u = ww[k] << 16;
      hi.u = ww[k] & 0xffff0000u;
      acc[2 * k] += lo.f;
      acc[2 * k + 1] += hi.f;
    }
  };
  addu(a, Tv[(size_t)node * 16 + q]);
  const int s = rowptr[node];
  const int e = rowptr[node + 1];
  int i = s;
  for (; i + 3 < e; i += 4) {
    const uint4 u0 = Tv[(size_t)colv[i] * 16 + q];
    const uint4 u1 = Tv[(size_t)colv[i + 1] * 16 + q];
    const uint4 u2 = Tv[(size_t)colv[i + 2] * 16 + q];
    const uint4 u3 = Tv[(size_t)colv[i + 3] * 16 + q];
    addu(a, u0);
    addu(b, u1);
    addu(c, u2);
    addu(d, u3);
  }
  for (; i < e; ++i) addu(a, Tv[(size_t)colv[i] * 16 + q]);
  const float ic = invc[node];
  uint4 o;
  uint32_t* ow = (uint32_t*)&o;
#pragma unroll
  for (int k = 0; k < 4; ++k) {
    const float r0 = (a[2 * k] + b[2 * k] + c[2 * k] + d[2 * k]) * ic;
    const float r1 = (a[2 * k + 1] + b[2 * k + 1] + c[2 * k + 1] + d[2 * k + 1]) * ic;
    ow[k] = (uint32_t)f2bf(r0) | ((uint32_t)f2bf(r1) << 16);
  }
  ((uint4*)sout)[(size_t)node * 16 + q] = o;
}

__global__ void beta_kernel(const float* __restrict__ beta, float* __restrict__ betas) {
  if (threadIdx.x == 0) {
    float mx = beta[0];
    for (int i = 1; i < NLAYER + 1; ++i) mx = fmaxf(mx, beta[i]);
    float e[NLAYER + 1];
    float s = 0.f;
    for (int i = 0; i < NLAYER + 1; ++i) {
      e[i] = expf(beta[i] - mx);
      s += e[i];
    }
    const float inv = 1.f / s;
    for (int i = 0; i < NLAYER + 1; ++i) betas[i] = e[i] * inv;
  }
}

// W[K][N] f32 -> Wt[N][K] bf16
__global__ void wconv_kernel(const float* __restrict__ W, ushort* __restrict__ Wt,
                             int K, int Nn) {
  const size_t matoff = (size_t)blockIdx.z * K * Nn;
  const int o = blockIdx.x * 256 + threadIdx.x;
  if (o >= K * Nn) return;
  const int nn = o / K;
  const int kk = o - nn * K;
  Wt[matoff + o] = f2bf(W[matoff + (size_t)kk * Nn + nn]);
}

// x f32 -> bf16, 8/thread
__global__ void xcast_kernel(const float* __restrict__ x, ushort* __restrict__ xb, int n8) {
  const int i = blockIdx.x * 256 + threadIdx.x;
  if (i >= n8) return;
  const f32x4 v0 = ((const f32x4*)x)[(size_t)i * 2];
  const f32x4 v1 = ((const f32x4*)x)[(size_t)i * 2 + 1];
  bf16x8 o;
#pragma unroll
  for (int q = 0; q < 4; ++q) {
    o[q] = (short)f2bf(v0[q]);
    o[q + 4] = (short)f2bf(v1[q]);
  }
  *(bf16x8*)(xb + (size_t)i * 8) = o;
}

// ---------------------------------------------------------------------------
extern "C" void kernel_launch(void* const* d_in, const int* in_sizes, int n_in,
                              void* d_out, int out_size, void* d_ws, size_t ws_size,
                              hipStream_t stream) {
  const float* x = (const float*)d_in[0];
  const int* eidx = (const int*)d_in[1];
  const float* Win = (const float*)d_in[2];
  const float* bin_ = (const float*)d_in[3];
  const float* W1 = (const float*)d_in[4];
  const float* b1 = (const float*)d_in[5];
  const float* W2 = (const float*)d_in[6];
  const float* b2 = (const float*)d_in[7];
  const float* U1 = (const float*)d_in[8];
  const float* c1 = (const float*)d_in[9];
  const float* U2 = (const float*)d_in[10];
  const float* c2 = (const float*)d_in[11];
  const float* ln_g = (const float*)d_in[12];
  const float* ln_b = (const float*)d_in[13];
  const float* beta = (const float*)d_in[14];
  float* outp = (float*)d_out;

  const int Nn = in_sizes[0] / 128;  // 50000
  const int E = in_sizes[1] / 2;     // 800000
  const int* srcv = eidx;
  const int* dstv = eidx + E;

  char* p = (char*)d_ws;
  auto alloc = [&](size_t bytes) {
    char* r = p;
    p += (bytes + 255) & ~(size_t)255;
    return r;
  };
  ushort* TSO = (ushort*)alloc((size_t)Nn * HIDC * 2);  // T | s (each Nn x 128)
  ushort* xbf = (ushort*)alloc((size_t)Nn * 128 * 2);
  ushort* WinT = (ushort*)alloc(128 * 256 * 2);
  ushort* W1T = (ushort*)alloc((size_t)NLAYER * 256 * 128 * 2);
  ushort* W2T = (ushort*)alloc((size_t)NLAYER * 128 * 256 * 2);
  ushort* U1T = (ushort*)alloc((size_t)NLAYER * 256 * 256 * 2);
  ushort* U2T = (ushort*)alloc((size_t)NLAYER * 256 * 256 * 2);
  int* deg = (int*)alloc((size_t)Nn * 4);
  int* rowptr = (int*)alloc((size_t)(Nn + 1) * 4);
  int* fillptr = (int*)alloc((size_t)Nn * 4);
  float* invc = (float*)alloc((size_t)Nn * 4);
  int* colv = (int*)alloc((size_t)E * 4);
  int* excl = (int*)alloc((size_t)Nn * 4);
  int* bsum = (int*)alloc(256 * 4);
  int* boff = (int*)alloc(256 * 4);
  float* betas = (float*)alloc(64);

  // z-history slots: as many as fit (G in [2, 11])
  const size_t ZS = (size_t)Nn * HIDC;
  const size_t slotB = ZS * 2;
  const size_t used = (size_t)(p - (char*)d_ws);
  int G = 2;
  if (ws_size > used + 4096) {
    size_t fit = (ws_size - used - 4096) / (slotB + 256);
    G = (int)(fit < 2 ? 2 : (fit > NLAYER + 1 ? NLAYER + 1 : fit));
  }
  ushort* zbase = (ushort*)alloc((size_t)G * slotB);

  ushort* T128 = TSO;
  ushort* s128 = TSO + (size_t)Nn * MSGC;

  const int nscan = (Nn + 255) / 256;
  const int mb128 = (Nn + 127) / 128;
  const int mb64 = (Nn + 63) / 64;
  const int nagg = (Nn + 15) / 16;
  const int total8 = (Nn * HIDC) / 8;

  hipMemsetAsync(deg, 0, (size_t)Nn * 4, stream);
  count_kernel<<<(E + 1023) / 1024, 256, 0, stream>>>(dstv, deg, E);
  scanA_kernel<<<nscan, 256, 0, stream>>>(deg, excl, bsum, Nn);
  scanB_kernel<<<1, 256, 0, stream>>>(bsum, boff, nscan);
  scanC_kernel<<<nscan, 256, 0, stream>>>(deg, excl, boff, rowptr, fillptr, invc, Nn, E);
  fill_kernel<<<(E + 1023) / 1024, 256, 0, stream>>>(srcv, dstv, fillptr, colv, E);
  beta_kernel<<<1, 64, 0, stream>>>(beta, betas);
  xcast_kernel<<<(Nn * 16 + 255) / 256, 256, 0, stream>>>(x, xbf, Nn * 16);
  wconv_kernel<<<dim3(128, 1, 1), 256, 0, stream>>>(Win, WinT, 128, 256);
  wconv_kernel<<<dim3(128, 1, NLAYER), 256, 0, stream>>>(W1, W1T, 256, 128);
  wconv_kernel<<<dim3(128, 1, NLAYER), 256, 0, stream>>>(W2, W2T, 128, 256);
  wconv_kernel<<<dim3(256, 1, NLAYER), 256, 0, stream>>>(U1, U1T, 256, 256);
  wconv_kernel<<<dim3(256, 1, NLAYER), 256, 0, stream>>>(U2, U2T, 256, 256);

  // fold bookkeeping
  int pend = 0, l0 = 0;
  bool first = true;
  auto flush = [&]() {
    if (pend > 0) {
      if (first)
        fold_kernel<1><<<(total8 + 255) / 256, 256, 0, stream>>>(zbase, ZS, betas, l0,
                                                                 pend, outp, total8);
      else
        fold_kernel<0><<<(total8 + 255) / 256, 256, 0, stream>>>(zbase, ZS, betas, l0,
                                                                 pend, outp, total8);
      first = false;
      l0 += pend;
      pend = 0;
    }
  };

  // z0 = x @ Win + bin -> slot 0
  ushort* zcur = zbase;
  gemm_win<<<mb128, 512, 0, stream>>>(xbf, WinT, bin_, zcur, Nn);
  pend = 1;

  for (int l = 0; l < NLAYER; ++l) {
    // T = bf16(relu(z @ W1 + b1))
    gemm_w1<<<mb128, 256, 0, stream>>>(zcur, W1T + (size_t)l * 256 * 128, b1 + l * 128,
                                       T128, Nn);
    // s = bf16(segmean(T))
    agg128_kernel<<<nagg, 256, 0, stream>>>(T128, rowptr, colv, invc, s128, Nn);
    // fold if all slots full
    if (pend == G) flush();
    // z' = LN(relu((s@W2+b2+z)@U1+c1)@U2+c2)*g+b  (h, O stay in LDS)
    ushort* znext = zbase + (size_t)pend * ZS;
    layer_fused<<<mb64, 512, 0, stream>>>(
        s128, zcur, W2T + (size_t)l * 128 * 256, b2 + l * 256,
        U1T + (size_t)l * 256 * 256, c1 + l * 256, U2T + (size_t)l * 256 * 256,
        c2 + l * 256, ln_g + l * 256, ln_b + l * 256, znext, Nn);
    zcur = znext;
    pend++;
  }
  flush();
}

// Round 10
// 1440.283 us; speedup vs baseline: 1.0185x; 1.0185x over previous
//
#include <hip/hip_runtime.h>
#include <stdint.h>

typedef __attribute__((ext_vector_type(4))) float f32x4;
typedef __attribute__((ext_vector_type(8))) short bf16x8;

#define HIDC 256
#define MSGC 128
#define NLAYER 10

__device__ __forceinline__ ushort f2bf(float f) {
  union { float f; uint32_t u; } a; a.f = f;
  uint32_t u = a.u;
  return (ushort)((u + 0x7fffu + ((u >> 16) & 1u)) >> 16);
}
__device__ __forceinline__ float bf2f(ushort h) {
  union { float f; uint32_t u; } a; a.u = ((uint32_t)h) << 16;
  return a.f;
}

// ---------------------------------------------------------------------------
// W1 GEMM: A bf16 [M x 256], B bf16 [128 x 256](transposed), C bf16 [M x 128].
// Tile 128x128, 4 waves, BK=64, RELU fused.
// ---------------------------------------------------------------------------
__global__ __launch_bounds__(256, 4) void gemm_w1(
    const ushort* __restrict__ A, const ushort* __restrict__ B,
    const float* __restrict__ bias, ushort* __restrict__ C, int M) {
  __shared__ ushort lA[128 * 64];
  __shared__ ushort lB[128 * 64];
  const int tid = threadIdx.x;
  const int m0 = blockIdx.x * 128;
  const int lane = tid & 63;
  const int w = tid >> 6;
  const int wm = (w >> 1) * 64;
  const int wn = (w & 1) * 64;
  const int rr = tid >> 3;  // 0..31
  const int cc = tid & 7;   // 0..7
  f32x4 acc[4][4] = {};

#pragma unroll
  for (int s = 0; s < 4; ++s) {  // K = 256
    const int k0 = s * 64;
#pragma unroll
    for (int p = 0; p < 4; ++p) {
      const int row = p * 32 + rr;
      const int gm = m0 + row;
      bf16x8 av = {0, 0, 0, 0, 0, 0, 0, 0};
      if (gm < M) av = *(const bf16x8*)(A + (size_t)gm * 256 + k0 + cc * 8);
      const uint32_t off = (uint32_t)((row * 128 + cc * 16) ^ ((row & 7) << 4));
      *(bf16x8*)((char*)lA + off) = av;
    }
#pragma unroll
    for (int p = 0; p < 4; ++p) {
      const int row = p * 32 + rr;
      bf16x8 bv = *(const bf16x8*)(B + (size_t)row * 256 + k0 + cc * 8);
      const uint32_t off = (uint32_t)((row * 128 + cc * 16) ^ ((row & 7) << 4));
      *(bf16x8*)((char*)lB + off) = bv;
    }
    __syncthreads();
#pragma unroll
    for (int kk = 0; kk < 2; ++kk) {
      bf16x8 ah[4];
#pragma unroll
      for (int i = 0; i < 4; ++i) {
        const int arow = wm + i * 16 + (lane & 15);
        const uint32_t ao =
            (uint32_t)((arow * 128 + kk * 64 + ((lane >> 4) * 16)) ^ ((arow & 7) << 4));
        ah[i] = *(const bf16x8*)((const char*)lA + ao);
      }
#pragma unroll
      for (int j = 0; j < 4; ++j) {
        const int brow = wn + j * 16 + (lane & 15);
        const uint32_t bo =
            (uint32_t)((brow * 128 + kk * 64 + ((lane >> 4) * 16)) ^ ((brow & 7) << 4));
        const bf16x8 bv = *(const bf16x8*)((const char*)lB + bo);
#pragma unroll
        for (int i = 0; i < 4; ++i)
          acc[i][j] = __builtin_amdgcn_mfma_f32_16x16x32_bf16(ah[i], bv, acc[i][j], 0, 0, 0);
      }
    }
    __syncthreads();
  }
  float bi[4];
#pragma unroll
  for (int j = 0; j < 4; ++j) bi[j] = bias[wn + j * 16 + (lane & 15)];
#pragma unroll
  for (int i = 0; i < 4; ++i) {
    const int gm0 = m0 + wm + i * 16 + ((lane >> 4) << 2);
#pragma unroll
    for (int r = 0; r < 4; ++r) {
      const int gm = gm0 + r;
      if (gm < M) {
        const size_t base = (size_t)gm * 128 + wn + (lane & 15);
#pragma unroll
        for (int j = 0; j < 4; ++j)
          C[base + j * 16] = f2bf(fmaxf(acc[i][j][r] + bi[j], 0.f));
      }
    }
  }
}

// ---------------------------------------------------------------------------
// Big GEMM: A bf16 [M x K], B bf16 [256 x K], tile 128x256, 8 waves, BK=64.
// LN=0: C = bf16(act(A@B^T + bias [+Z]))
// LN=1: C = bf16(LN(A@B^T + bias)*g + b_)
// ---------------------------------------------------------------------------
template <int RELU, int ADDZ, int LN>
__global__ __launch_bounds__(512, 4) void gemm_big(
    const ushort* __restrict__ A, const ushort* __restrict__ B,
    const float* __restrict__ bias, const ushort* __restrict__ Z,
    ushort* __restrict__ C, const float* __restrict__ g,
    const float* __restrict__ b_, int M, int K) {
  __shared__ ushort lA[128 * 64];
  __shared__ ushort lB[256 * 64];
  __shared__ float sstat[2][4][128];
  const int tid = threadIdx.x;
  const int m0 = blockIdx.x * 128;
  const int lane = tid & 63;
  const int w = tid >> 6;        // 0..7
  const int wm = (w >> 2) * 64;  // 0,64
  const int wn = (w & 3) * 64;   // 0,64,128,192
  const int rr = tid >> 3;       // 0..63
  const int cc = tid & 7;        // 0..7
  f32x4 acc[4][4] = {};

  const int nsteps = K >> 6;
  for (int s = 0; s < nsteps; ++s) {
    const int k0 = s * 64;
#pragma unroll
    for (int p = 0; p < 2; ++p) {
      const int row = p * 64 + rr;
      const int gm = m0 + row;
      bf16x8 av = {0, 0, 0, 0, 0, 0, 0, 0};
      if (gm < M) av = *(const bf16x8*)(A + (size_t)gm * K + k0 + cc * 8);
      const uint32_t off = (uint32_t)((row * 128 + cc * 16) ^ ((row & 7) << 4));
      *(bf16x8*)((char*)lA + off) = av;
    }
#pragma unroll
    for (int p = 0; p < 4; ++p) {
      const int row = p * 64 + rr;
      bf16x8 bv = *(const bf16x8*)(B + (size_t)row * K + k0 + cc * 8);
      const uint32_t off = (uint32_t)((row * 128 + cc * 16) ^ ((row & 7) << 4));
      *(bf16x8*)((char*)lB + off) = bv;
    }
    __syncthreads();
#pragma unroll
    for (int kk = 0; kk < 2; ++kk) {
      bf16x8 ah[4];
#pragma unroll
      for (int i = 0; i < 4; ++i) {
        const int arow = wm + i * 16 + (lane & 15);
        const uint32_t ao =
            (uint32_t)((arow * 128 + kk * 64 + ((lane >> 4) * 16)) ^ ((arow & 7) << 4));
        ah[i] = *(const bf16x8*)((const char*)lA + ao);
      }
#pragma unroll
      for (int j = 0; j < 4; ++j) {
        const int brow = wn + j * 16 + (lane & 15);
        const uint32_t bo =
            (uint32_t)((brow * 128 + kk * 64 + ((lane >> 4) * 16)) ^ ((brow & 7) << 4));
        const bf16x8 bv = *(const bf16x8*)((const char*)lB + bo);
#pragma unroll
        for (int i = 0; i < 4; ++i)
          acc[i][j] = __builtin_amdgcn_mfma_f32_16x16x32_bf16(ah[i], bv, acc[i][j], 0, 0, 0);
      }
    }
    __syncthreads();
  }

  float bi[4];
#pragma unroll
  for (int j = 0; j < 4; ++j) bi[j] = bias[wn + j * 16 + (lane & 15)];

  if (LN) {
    float gv[4], bv[4];
#pragma unroll
    for (int j = 0; j < 4; ++j) {
      gv[j] = g[wn + j * 16 + (lane & 15)];
      bv[j] = b_[wn + j * 16 + (lane & 15)];
    }
#pragma unroll
    for (int i = 0; i < 4; ++i) {
#pragma unroll
      for (int r = 0; r < 4; ++r) {
        float s1 = 0.f, s2 = 0.f;
#pragma unroll
        for (int j = 0; j < 4; ++j) {
          float v = acc[i][j][r] + bi[j];
          acc[i][j][r] = v;
          s1 += v;
          s2 += v * v;
        }
#pragma unroll
        for (int d = 1; d < 16; d <<= 1) {
          s1 += __shfl_xor(s1, d);
          s2 += __shfl_xor(s2, d);
        }
        if ((lane & 15) == 0) {
          const int rl = wm + i * 16 + ((lane >> 4) << 2) + r;
          sstat[0][w & 3][rl] = s1;
          sstat[1][w & 3][rl] = s2;
        }
      }
    }
    __syncthreads();
#pragma unroll
    for (int i = 0; i < 4; ++i) {
#pragma unroll
      for (int r = 0; r < 4; ++r) {
        const int rl = wm + i * 16 + ((lane >> 4) << 2) + r;
        const float s1 = sstat[0][0][rl] + sstat[0][1][rl] + sstat[0][2][rl] + sstat[0][3][rl];
        const float s2 = sstat[1][0][rl] + sstat[1][1][rl] + sstat[1][2][rl] + sstat[1][3][rl];
        const float mu = s1 * (1.f / 256.f);
        const float var = s2 * (1.f / 256.f) - mu * mu;
        const float rs = rsqrtf(var + 1e-5f);
        const int gm = m0 + rl;
        if (gm < M) {
          const size_t base = (size_t)gm * 256 + wn + (lane & 15);
#pragma unroll
          for (int j = 0; j < 4; ++j)
            C[base + j * 16] = f2bf((acc[i][j][r] - mu) * rs * gv[j] + bv[j]);
        }
      }
    }
  } else {
#pragma unroll
    for (int i = 0; i < 4; ++i) {
      const int gm0 = m0 + wm + i * 16 + ((lane >> 4) << 2);
#pragma unroll
      for (int r = 0; r < 4; ++r) {
        const int gm = gm0 + r;
        if (gm < M) {
          const size_t base = (size_t)gm * 256 + wn + (lane & 15);
#pragma unroll
          for (int j = 0; j < 4; ++j) {
            float v = acc[i][j][r] + bi[j];
            if (ADDZ) v += bf2f(Z[base + j * 16]);
            if (RELU) v = fmaxf(v, 0.f);
            C[base + j * 16] = f2bf(v);
          }
        }
      }
    }
  }
}

// ---------------------------------------------------------------------------
// Fold: outp (+)= sum_{k<P} betas[l0+k] * bf2f(zbase[k][i]); 8 elems/thread.
// ---------------------------------------------------------------------------
template <int WRITE>
__global__ __launch_bounds__(256) void fold_kernel(
    const ushort* __restrict__ zbase, size_t ZS, const float* __restrict__ betas,
    int l0, int P, float* __restrict__ outp, int total8) {
  const int i = blockIdx.x * 256 + threadIdx.x;
  if (i >= total8) return;
  float a[8] = {};
  for (int k = 0; k < P; ++k) {
    const float bl = betas[l0 + k];
    const uint4 u = ((const uint4*)(zbase + k * ZS))[i];
    const uint32_t ww[4] = {u.x, u.y, u.z, u.w};
#pragma unroll
    for (int q = 0; q < 4; ++q) {
      union { uint32_t u; float f; } lo, hi;
      lo.u = ww[q] << 16;
      hi.u = ww[q] & 0xffff0000u;
      a[2 * q] += bl * lo.f;
      a[2 * q + 1] += bl * hi.f;
    }
  }
  f32x4 o0 = {a[0], a[1], a[2], a[3]};
  f32x4 o1 = {a[4], a[5], a[6], a[7]};
  if (WRITE) {
    ((f32x4*)outp)[(size_t)i * 2] = o0;
    ((f32x4*)outp)[(size_t)i * 2 + 1] = o1;
  } else {
    f32x4 p0 = ((f32x4*)outp)[(size_t)i * 2];
    f32x4 p1 = ((f32x4*)outp)[(size_t)i * 2 + 1];
    ((f32x4*)outp)[(size_t)i * 2] = p0 + o0;
    ((f32x4*)outp)[(size_t)i * 2 + 1] = p1 + o1;
  }
}

// ---------------------------------------------------------------------------
// CSR build (parallel scan), 4 edges/thread for atomic ILP
// ---------------------------------------------------------------------------
__global__ void count_kernel(const int* __restrict__ dstv, int* __restrict__ deg, int E) {
  const int i = (blockIdx.x * 256 + threadIdx.x) * 4;
#pragma unroll
  for (int k = 0; k < 4; ++k)
    if (i + k < E) atomicAdd(&deg[dstv[i + k]], 1);
}

__global__ void scanA_kernel(const int* __restrict__ deg, int* __restrict__ excl,
                             int* __restrict__ bsum, int n) {
  __shared__ int sm[256];
  const int i = blockIdx.x * 256 + threadIdx.x;
  const int v = (i < n) ? deg[i] : 0;
  sm[threadIdx.x] = v;
  __syncthreads();
  for (int off = 1; off < 256; off <<= 1) {
    int t = (threadIdx.x >= off) ? sm[threadIdx.x - off] : 0;
    __syncthreads();
    sm[threadIdx.x] += t;
    __syncthreads();
  }
  if (i < n) excl[i] = sm[threadIdx.x] - v;
  if (threadIdx.x == 255) bsum[blockIdx.x] = sm[255];
}

__global__ void scanB_kernel(const int* __restrict__ bsum, int* __restrict__ boff, int nb) {
  __shared__ int sm[256];
  const int v = (threadIdx.x < nb) ? bsum[threadIdx.x] : 0;
  sm[threadIdx.x] = v;
  __syncthreads();
  for (int off = 1; off < 256; off <<= 1) {
    int t = (threadIdx.x >= off) ? sm[threadIdx.x - off] : 0;
    __syncthreads();
    sm[threadIdx.x] += t;
    __syncthreads();
  }
  if (threadIdx.x < nb) boff[threadIdx.x] = sm[threadIdx.x] - v;
}

__global__ void scanC_kernel(const int* __restrict__ deg, const int* __restrict__ excl,
                             const int* __restrict__ boff, int* __restrict__ rowptr,
                             int* __restrict__ fillptr, float* __restrict__ invc,
                             int n, int E) {
  const int i = blockIdx.x * 256 + threadIdx.x;
  if (i < n) {
    const int r = excl[i] + boff[blockIdx.x];
    rowptr[i] = r;
    fillptr[i] = r;
    invc[i] = 1.0f / (float)(deg[i] + 1);
  }
  if (i == 0) rowptr[n] = E;
}

__global__ void fill_kernel(const int* __restrict__ srcv, const int* __restrict__ dstv,
                            int* __restrict__ fillptr, int* __restrict__ colv, int E) {
  const int i = (blockIdx.x * 256 + threadIdx.x) * 4;
#pragma unroll
  for (int k = 0; k < 4; ++k)
    if (i + k < E) {
      int p = atomicAdd(&fillptr[dstv[i + k]], 1);
      colv[p] = srcv[i + k];
    }
}

// ---------------------------------------------------------------------------
// 128-d aggregation, quarter-wave (16 lanes x 16B) per node, x4 unroll.
// ---------------------------------------------------------------------------
__global__ __launch_bounds__(256) void agg128_kernel(
    const ushort* __restrict__ T, const int* __restrict__ rowptr,
    const int* __restrict__ colv, const float* __restrict__ invc,
    ushort* __restrict__ sout, int n) {
  const int node = blockIdx.x * 16 + (threadIdx.x >> 4);
  if (node >= n) return;
  const int q = threadIdx.x & 15;
  const uint4* Tv = (const uint4*)T;  // row = 16 x 16B chunks
  float a[8] = {}, b[8] = {}, c[8] = {}, d[8] = {};
  auto addu = [](float* acc, uint4 u) {
    const uint32_t ww[4] = {u.x, u.y, u.z, u.w};
#pragma unroll
    for (int k = 0; k < 4; ++k) {
      union { uint32_t u; float f; } lo, hi;
      lo.u = ww[k] << 16;
      hi.u = ww[k] & 0xffff0000u;
      acc[2 * k] += lo.f;
      acc[2 * k + 1] += hi.f;
    }
  };
  addu(a, Tv[(size_t)node * 16 + q]);
  const int s = rowptr[node];
  const int e = rowptr[node + 1];
  int i = s;
  for (; i + 3 < e; i += 4) {
    const uint4 u0 = Tv[(size_t)colv[i] * 16 + q];
    const uint4 u1 = Tv[(size_t)colv[i + 1] * 16 + q];
    const uint4 u2 = Tv[(size_t)colv[i + 2] * 16 + q];
    const uint4 u3 = Tv[(size_t)colv[i + 3] * 16 + q];
    addu(a, u0);
    addu(b, u1);
    addu(c, u2);
    addu(d, u3);
  }
  for (; i < e; ++i) addu(a, Tv[(size_t)colv[i] * 16 + q]);
  const float ic = invc[node];
  uint4 o;
  uint32_t* ow = (uint32_t*)&o;
#pragma unroll
  for (int k = 0; k < 4; ++k) {
    const float r0 = (a[2 * k] + b[2 * k] + c[2 * k] + d[2 * k]) * ic;
    const float r1 = (a[2 * k + 1] + b[2 * k + 1] + c[2 * k + 1] + d[2 * k + 1]) * ic;
    ow[k] = (uint32_t)f2bf(r0) | ((uint32_t)f2bf(r1) << 16);
  }
  ((uint4*)sout)[(size_t)node * 16 + q] = o;
}

__global__ void beta_kernel(const float* __restrict__ beta, float* __restrict__ betas) {
  if (threadIdx.x == 0) {
    float mx = beta[0];
    for (int i = 1; i < NLAYER + 1; ++i) mx = fmaxf(mx, beta[i]);
    float e[NLAYER + 1];
    float s = 0.f;
    for (int i = 0; i < NLAYER + 1; ++i) {
      e[i] = expf(beta[i] - mx);
      s += e[i];
    }
    const float inv = 1.f / s;
    for (int i = 0; i < NLAYER + 1; ++i) betas[i] = e[i] * inv;
  }
}

// W[K][N] f32 -> Wt[N][K] bf16
__global__ void wconv_kernel(const float* __restrict__ W, ushort* __restrict__ Wt,
                             int K, int Nn) {
  const size_t matoff = (size_t)blockIdx.z * K * Nn;
  const int o = blockIdx.x * 256 + threadIdx.x;
  if (o >= K * Nn) return;
  const int nn = o / K;
  const int kk = o - nn * K;
  Wt[matoff + o] = f2bf(W[matoff + (size_t)kk * Nn + nn]);
}

// U1 and U2 (both [L][256][256]) in one launch: z < NLAYER -> U1, else U2
__global__ void wconvU_kernel(const float* __restrict__ U1, const float* __restrict__ U2,
                              ushort* __restrict__ U1T, ushort* __restrict__ U2T) {
  const int li = blockIdx.z;
  const float* W = (li < NLAYER) ? U1 : U2;
  ushort* Wt = (li < NLAYER) ? U1T : U2T;
  const size_t matoff = (size_t)(li % NLAYER) * 256 * 256;
  const int o = blockIdx.x * 256 + threadIdx.x;
  const int nn = o >> 8;
  const int kk = o & 255;
  Wt[matoff + o] = f2bf(W[matoff + (size_t)kk * 256 + nn]);
}

// x f32 -> bf16, 8/thread
__global__ void xcast_kernel(const float* __restrict__ x, ushort* __restrict__ xb, int n8) {
  const int i = blockIdx.x * 256 + threadIdx.x;
  if (i >= n8) return;
  const f32x4 v0 = ((const f32x4*)x)[(size_t)i * 2];
  const f32x4 v1 = ((const f32x4*)x)[(size_t)i * 2 + 1];
  bf16x8 o;
#pragma unroll
  for (int q = 0; q < 4; ++q) {
    o[q] = (short)f2bf(v0[q]);
    o[q + 4] = (short)f2bf(v1[q]);
  }
  *(bf16x8*)(xb + (size_t)i * 8) = o;
}

// Win GEMM (z0): A bf16 [M x 128], B bf16 [256 x 128], C bf16 [M x 256].
__global__ __launch_bounds__(512, 4) void gemm_win(
    const ushort* __restrict__ A, const ushort* __restrict__ B,
    const float* __restrict__ bias, ushort* __restrict__ C, int M) {
  __shared__ ushort lA[128 * 64];
  __shared__ ushort lB[256 * 64];
  const int tid = threadIdx.x;
  const int m0 = blockIdx.x * 128;
  const int lane = tid & 63;
  const int w = tid >> 6;
  const int wm = (w >> 2) * 64;
  const int wn = (w & 3) * 64;
  const int rr = tid >> 3;
  const int cc = tid & 7;
  f32x4 acc[4][4] = {};
  const int K = 128;

#pragma unroll
  for (int s = 0; s < 2; ++s) {
    const int k0 = s * 64;
#pragma unroll
    for (int p = 0; p < 2; ++p) {
      const int row = p * 64 + rr;
      const int gm = m0 + row;
      bf16x8 av = {0, 0, 0, 0, 0, 0, 0, 0};
      if (gm < M) av = *(const bf16x8*)(A + (size_t)gm * K + k0 + cc * 8);
      const uint32_t off = (uint32_t)((row * 128 + cc * 16) ^ ((row & 7) << 4));
      *(bf16x8*)((char*)lA + off) = av;
    }
#pragma unroll
    for (int p = 0; p < 4; ++p) {
      const int row = p * 64 + rr;
      bf16x8 bv = *(const bf16x8*)(B + (size_t)row * K + k0 + cc * 8);
      const uint32_t off = (uint32_t)((row * 128 + cc * 16) ^ ((row & 7) << 4));
      *(bf16x8*)((char*)lB + off) = bv;
    }
    __syncthreads();
#pragma unroll
    for (int kk = 0; kk < 2; ++kk) {
      bf16x8 ah[4];
#pragma unroll
      for (int i = 0; i < 4; ++i) {
        const int arow = wm + i * 16 + (lane & 15);
        const uint32_t ao =
            (uint32_t)((arow * 128 + kk * 64 + ((lane >> 4) * 16)) ^ ((arow & 7) << 4));
        ah[i] = *(const bf16x8*)((const char*)lA + ao);
      }
#pragma unroll
      for (int j = 0; j < 4; ++j) {
        const int brow = wn + j * 16 + (lane & 15);
        const uint32_t bo =
            (uint32_t)((brow * 128 + kk * 64 + ((lane >> 4) * 16)) ^ ((brow & 7) << 4));
        const bf16x8 bv = *(const bf16x8*)((const char*)lB + bo);
#pragma unroll
        for (int i = 0; i < 4; ++i)
          acc[i][j] = __builtin_amdgcn_mfma_f32_16x16x32_bf16(ah[i], bv, acc[i][j], 0, 0, 0);
      }
    }
    __syncthreads();
  }
  float bi[4];
#pragma unroll
  for (int j = 0; j < 4; ++j) bi[j] = bias[wn + j * 16 + (lane & 15)];
#pragma unroll
  for (int i = 0; i < 4; ++i) {
    const int gm0 = m0 + wm + i * 16 + ((lane >> 4) << 2);
#pragma unroll
    for (int r = 0; r < 4; ++r) {
      const int gm = gm0 + r;
      if (gm < M) {
        const size_t base = (size_t)gm * 256 + wn + (lane & 15);
#pragma unroll
        for (int j = 0; j < 4; ++j)
          C[base + j * 16] = f2bf(acc[i][j][r] + bi[j]);
      }
    }
  }
}

// ---------------------------------------------------------------------------
extern "C" void kernel_launch(void* const* d_in, const int* in_sizes, int n_in,
                              void* d_out, int out_size, void* d_ws, size_t ws_size,
                              hipStream_t stream) {
  const float* x = (const float*)d_in[0];
  const int* eidx = (const int*)d_in[1];
  const float* Win = (const float*)d_in[2];
  const float* bin_ = (const float*)d_in[3];
  const float* W1 = (const float*)d_in[4];
  const float* b1 = (const float*)d_in[5];
  const float* W2 = (const float*)d_in[6];
  const float* b2 = (const float*)d_in[7];
  const float* U1 = (const float*)d_in[8];
  const float* c1 = (const float*)d_in[9];
  const float* U2 = (const float*)d_in[10];
  const float* c2 = (const float*)d_in[11];
  const float* ln_g = (const float*)d_in[12];
  const float* ln_b = (const float*)d_in[13];
  const float* beta = (const float*)d_in[14];
  float* outp = (float*)d_out;

  const int Nn = in_sizes[0] / 128;  // 50000
  const int E = in_sizes[1] / 2;     // 800000
  const int* srcv = eidx;
  const int* dstv = eidx + E;

  char* p = (char*)d_ws;
  auto alloc = [&](size_t bytes) {
    char* r = p;
    p += (bytes + 255) & ~(size_t)255;
    return r;
  };
  ushort* hbuf = (ushort*)alloc((size_t)Nn * HIDC * 2);  // h bf16
  ushort* TSO = (ushort*)alloc((size_t)Nn * HIDC * 2);   // T | s, later O
  ushort* xbf = (ushort*)alloc((size_t)Nn * 128 * 2);
  ushort* WinT = (ushort*)alloc(128 * 256 * 2);
  ushort* W1T = (ushort*)alloc((size_t)NLAYER * 256 * 128 * 2);
  ushort* W2T = (ushort*)alloc((size_t)NLAYER * 128 * 256 * 2);
  ushort* U1T = (ushort*)alloc((size_t)NLAYER * 256 * 256 * 2);
  ushort* U2T = (ushort*)alloc((size_t)NLAYER * 256 * 256 * 2);
  int* deg = (int*)alloc((size_t)Nn * 4);
  int* rowptr = (int*)alloc((size_t)(Nn + 1) * 4);
  int* fillptr = (int*)alloc((size_t)Nn * 4);
  float* invc = (float*)alloc((size_t)Nn * 4);
  int* colv = (int*)alloc((size_t)E * 4);
  int* excl = (int*)alloc((size_t)Nn * 4);
  int* bsum = (int*)alloc(256 * 4);
  int* boff = (int*)alloc(256 * 4);
  float* betas = (float*)alloc(64);

  // z-history slots: as many as fit (G in [2, 11])
  const size_t ZS = (size_t)Nn * HIDC;
  const size_t slotB = ZS * 2;
  const size_t used = (size_t)(p - (char*)d_ws);
  int G = 2;
  if (ws_size > used + 4096) {
    size_t fit = (ws_size - used - 4096) / (slotB + 256);
    G = (int)(fit < 2 ? 2 : (fit > NLAYER + 1 ? NLAYER + 1 : fit));
  }
  ushort* zbase = (ushort*)alloc((size_t)G * slotB);

  ushort* T128 = TSO;
  ushort* s128 = TSO + (size_t)Nn * MSGC;
  ushort* Obuf = TSO;  // reuses T|s after both consumed

  const int nscan = (Nn + 255) / 256;
  const int mb128 = (Nn + 127) / 128;
  const int nagg = (Nn + 15) / 16;
  const int total8 = (Nn * HIDC) / 8;

  hipMemsetAsync(deg, 0, (size_t)Nn * 4, stream);
  count_kernel<<<(E + 1023) / 1024, 256, 0, stream>>>(dstv, deg, E);
  scanA_kernel<<<nscan, 256, 0, stream>>>(deg, excl, bsum, Nn);
  scanB_kernel<<<1, 256, 0, stream>>>(bsum, boff, nscan);
  scanC_kernel<<<nscan, 256, 0, stream>>>(deg, excl, boff, rowptr, fillptr, invc, Nn, E);
  fill_kernel<<<(E + 1023) / 1024, 256, 0, stream>>>(srcv, dstv, fillptr, colv, E);
  beta_kernel<<<1, 64, 0, stream>>>(beta, betas);
  xcast_kernel<<<(Nn * 16 + 255) / 256, 256, 0, stream>>>(x, xbf, Nn * 16);
  wconv_kernel<<<dim3(128, 1, 1), 256, 0, stream>>>(Win, WinT, 128, 256);
  wconv_kernel<<<dim3(128, 1, NLAYER), 256, 0, stream>>>(W1, W1T, 256, 128);
  wconv_kernel<<<dim3(128, 1, NLAYER), 256, 0, stream>>>(W2, W2T, 128, 256);
  wconvU_kernel<<<dim3(256, 1, 2 * NLAYER), 256, 0, stream>>>(U1, U2, U1T, U2T);

  // fold bookkeeping
  int pend = 0, l0 = 0;
  bool first = true;
  auto flush = [&]() {
    if (pend > 0) {
      if (first)
        fold_kernel<1><<<(total8 + 255) / 256, 256, 0, stream>>>(zbase, ZS, betas, l0,
                                                                 pend, outp, total8);
      else
        fold_kernel<0><<<(total8 + 255) / 256, 256, 0, stream>>>(zbase, ZS, betas, l0,
                                                                 pend, outp, total8);
      first = false;
      l0 += pend;
      pend = 0;
    }
  };

  // z0 = x @ Win + bin -> slot 0
  ushort* zcur = zbase;
  gemm_win<<<mb128, 512, 0, stream>>>(xbf, WinT, bin_, zcur, Nn);
  pend = 1;

  for (int l = 0; l < NLAYER; ++l) {
    // T = bf16(relu(z @ W1 + b1))
    gemm_w1<<<mb128, 256, 0, stream>>>(zcur, W1T + (size_t)l * 256 * 128, b1 + l * 128,
                                       T128, Nn);
    // s = bf16(segmean(T))
    agg128_kernel<<<nagg, 256, 0, stream>>>(T128, rowptr, colv, invc, s128, Nn);
    // h = bf16(z + s @ W2 + b2)
    gemm_big<0, 1, 0><<<mb128, 512, 0, stream>>>(s128, W2T + (size_t)l * 128 * 256,
                                                 b2 + l * 256, zcur, hbuf, nullptr,
                                                 nullptr, Nn, 128);
    // O = bf16(relu(h @ U1 + c1))
    gemm_big<1, 0, 0><<<mb128, 512, 0, stream>>>(hbuf, U1T + (size_t)l * 256 * 256,
                                                 c1 + l * 256, nullptr, Obuf, nullptr,
                                                 nullptr, Nn, 256);
    // fold if all slots full
    if (pend == G) flush();
    // z' = bf16(LN(O @ U2 + c2)*g + b)
    ushort* znext = zbase + (size_t)pend * ZS;
    gemm_big<0, 0, 1><<<mb128, 512, 0, stream>>>(Obuf, U2T + (size_t)l * 256 * 256,
                                                 c2 + l * 256, nullptr, znext,
                                                 ln_g + l * 256, ln_b + l * 256, Nn, 256);
    zcur = znext;
    pend++;
  }
  flush();
}

// Round 11
// 1286.899 us; speedup vs baseline: 1.1399x; 1.1192x over previous
//
#include <hip/hip_runtime.h>
#include <stdint.h>

typedef __attribute__((ext_vector_type(4))) float f32x4;
typedef __attribute__((ext_vector_type(8))) short bf16x8;

#define HIDC 256
#define MSGC 128
#define NLAYER 10

__device__ __forceinline__ ushort f2bf(float f) {
  union { float f; uint32_t u; } a; a.f = f;
  uint32_t u = a.u;
  return (ushort)((u + 0x7fffu + ((u >> 16) & 1u)) >> 16);
}
__device__ __forceinline__ float bf2f(ushort h) {
  union { float f; uint32_t u; } a; a.u = ((uint32_t)h) << 16;
  return a.f;
}

// ---------------------------------------------------------------------------
// W1 GEMM: A bf16 [M x 256], B bf16 [128 x 256](T), C bf16 [M x 128].
// Tile 64x128, 4 waves (2x2), BK=64, RELU fused. 24 KB LDS.
// ---------------------------------------------------------------------------
__global__ __launch_bounds__(256, 4) void gemm_w1_64(
    const ushort* __restrict__ A, const ushort* __restrict__ B,
    const float* __restrict__ bias, ushort* __restrict__ C, int M) {
  __shared__ ushort lA[64 * 64];
  __shared__ ushort lB[128 * 64];
  const int tid = threadIdx.x;
  const int m0 = blockIdx.x * 64;
  const int lane = tid & 63;
  const int w = tid >> 6;
  const int wm = (w >> 1) * 32;  // 0,32
  const int wn = (w & 1) * 64;   // 0,64
  const int rr = tid >> 3;       // 0..31
  const int cc = tid & 7;        // 0..7
  f32x4 acc[2][4] = {};

#pragma unroll
  for (int s = 0; s < 4; ++s) {  // K = 256
    const int k0 = s * 64;
#pragma unroll
    for (int p = 0; p < 2; ++p) {
      const int row = p * 32 + rr;
      const int gm = m0 + row;
      bf16x8 av = {0, 0, 0, 0, 0, 0, 0, 0};
      if (gm < M) av = *(const bf16x8*)(A + (size_t)gm * 256 + k0 + cc * 8);
      const uint32_t off = (uint32_t)((row * 128 + cc * 16) ^ ((row & 7) << 4));
      *(bf16x8*)((char*)lA + off) = av;
    }
#pragma unroll
    for (int p = 0; p < 4; ++p) {
      const int row = p * 32 + rr;
      bf16x8 bv = *(const bf16x8*)(B + (size_t)row * 256 + k0 + cc * 8);
      const uint32_t off = (uint32_t)((row * 128 + cc * 16) ^ ((row & 7) << 4));
      *(bf16x8*)((char*)lB + off) = bv;
    }
    __syncthreads();
#pragma unroll
    for (int kk = 0; kk < 2; ++kk) {
      bf16x8 ah[2];
#pragma unroll
      for (int i = 0; i < 2; ++i) {
        const int arow = wm + i * 16 + (lane & 15);
        const uint32_t ao =
            (uint32_t)((arow * 128 + kk * 64 + ((lane >> 4) * 16)) ^ ((arow & 7) << 4));
        ah[i] = *(const bf16x8*)((const char*)lA + ao);
      }
#pragma unroll
      for (int j = 0; j < 4; ++j) {
        const int brow = wn + j * 16 + (lane & 15);
        const uint32_t bo =
            (uint32_t)((brow * 128 + kk * 64 + ((lane >> 4) * 16)) ^ ((brow & 7) << 4));
        const bf16x8 bv = *(const bf16x8*)((const char*)lB + bo);
#pragma unroll
        for (int i = 0; i < 2; ++i)
          acc[i][j] = __builtin_amdgcn_mfma_f32_16x16x32_bf16(ah[i], bv, acc[i][j], 0, 0, 0);
      }
    }
    __syncthreads();
  }
  float bi[4];
#pragma unroll
  for (int j = 0; j < 4; ++j) bi[j] = bias[wn + j * 16 + (lane & 15)];
#pragma unroll
  for (int i = 0; i < 2; ++i) {
    const int gm0 = m0 + wm + i * 16 + ((lane >> 4) << 2);
#pragma unroll
    for (int r = 0; r < 4; ++r) {
      const int gm = gm0 + r;
      if (gm < M) {
        const size_t base = (size_t)gm * 128 + wn + (lane & 15);
#pragma unroll
        for (int j = 0; j < 4; ++j)
          C[base + j * 16] = f2bf(fmaxf(acc[i][j][r] + bi[j], 0.f));
      }
    }
  }
}

// ---------------------------------------------------------------------------
// Big GEMM 64-row: A bf16 [M x K], B bf16 [256 x K], tile 64x256, 4 waves.
// 42 KB LDS -> 3 blocks/CU; grid = ceil(M/64) = 782.
// LN=0: C = bf16(act(A@B^T + bias [+Z]))
// LN=1: C = bf16(LN(A@B^T + bias)*g + b_)
// ---------------------------------------------------------------------------
template <int RELU, int ADDZ, int LN>
__global__ __launch_bounds__(256, 3) void gemm_big64(
    const ushort* __restrict__ A, const ushort* __restrict__ B,
    const float* __restrict__ bias, const ushort* __restrict__ Z,
    ushort* __restrict__ C, const float* __restrict__ g,
    const float* __restrict__ b_, int M, int K) {
  __shared__ ushort lA[64 * 64];
  __shared__ ushort lB[256 * 64];
  __shared__ float sstat[2][4][64];
  const int tid = threadIdx.x;
  const int m0 = blockIdx.x * 64;
  const int lane = tid & 63;
  const int w = tid >> 6;      // 0..3
  const int wn = w * 64;       // col slice per wave
  const int rr = tid >> 3;     // 0..31
  const int cc = tid & 7;      // 0..7
  f32x4 acc[4][4] = {};

  const int nsteps = K >> 6;
  for (int s = 0; s < nsteps; ++s) {
    const int k0 = s * 64;
#pragma unroll
    for (int p = 0; p < 2; ++p) {
      const int row = p * 32 + rr;
      const int gm = m0 + row;
      bf16x8 av = {0, 0, 0, 0, 0, 0, 0, 0};
      if (gm < M) av = *(const bf16x8*)(A + (size_t)gm * K + k0 + cc * 8);
      const uint32_t off = (uint32_t)((row * 128 + cc * 16) ^ ((row & 7) << 4));
      *(bf16x8*)((char*)lA + off) = av;
    }
#pragma unroll
    for (int p = 0; p < 8; ++p) {
      const int row = p * 32 + rr;
      bf16x8 bv = *(const bf16x8*)(B + (size_t)row * K + k0 + cc * 8);
      const uint32_t off = (uint32_t)((row * 128 + cc * 16) ^ ((row & 7) << 4));
      *(bf16x8*)((char*)lB + off) = bv;
    }
    __syncthreads();
#pragma unroll
    for (int kk = 0; kk < 2; ++kk) {
      bf16x8 ah[4];
#pragma unroll
      for (int i = 0; i < 4; ++i) {
        const int arow = i * 16 + (lane & 15);
        const uint32_t ao =
            (uint32_t)((arow * 128 + kk * 64 + ((lane >> 4) * 16)) ^ ((arow & 7) << 4));
        ah[i] = *(const bf16x8*)((const char*)lA + ao);
      }
#pragma unroll
      for (int j = 0; j < 4; ++j) {
        const int brow = wn + j * 16 + (lane & 15);
        const uint32_t bo =
            (uint32_t)((brow * 128 + kk * 64 + ((lane >> 4) * 16)) ^ ((brow & 7) << 4));
        const bf16x8 bv = *(const bf16x8*)((const char*)lB + bo);
#pragma unroll
        for (int i = 0; i < 4; ++i)
          acc[i][j] = __builtin_amdgcn_mfma_f32_16x16x32_bf16(ah[i], bv, acc[i][j], 0, 0, 0);
      }
    }
    __syncthreads();
  }

  float bi[4];
#pragma unroll
  for (int j = 0; j < 4; ++j) bi[j] = bias[wn + j * 16 + (lane & 15)];

  if (LN) {
    float gv[4], bv[4];
#pragma unroll
    for (int j = 0; j < 4; ++j) {
      gv[j] = g[wn + j * 16 + (lane & 15)];
      bv[j] = b_[wn + j * 16 + (lane & 15)];
    }
#pragma unroll
    for (int i = 0; i < 4; ++i) {
#pragma unroll
      for (int r = 0; r < 4; ++r) {
        float s1 = 0.f, s2 = 0.f;
#pragma unroll
        for (int j = 0; j < 4; ++j) {
          float v = acc[i][j][r] + bi[j];
          acc[i][j][r] = v;
          s1 += v;
          s2 += v * v;
        }
#pragma unroll
        for (int d = 1; d < 16; d <<= 1) {
          s1 += __shfl_xor(s1, d);
          s2 += __shfl_xor(s2, d);
        }
        if ((lane & 15) == 0) {
          const int rl = i * 16 + ((lane >> 4) << 2) + r;
          sstat[0][w][rl] = s1;
          sstat[1][w][rl] = s2;
        }
      }
    }
    __syncthreads();
#pragma unroll
    for (int i = 0; i < 4; ++i) {
#pragma unroll
      for (int r = 0; r < 4; ++r) {
        const int rl = i * 16 + ((lane >> 4) << 2) + r;
        const float s1 = sstat[0][0][rl] + sstat[0][1][rl] + sstat[0][2][rl] + sstat[0][3][rl];
        const float s2 = sstat[1][0][rl] + sstat[1][1][rl] + sstat[1][2][rl] + sstat[1][3][rl];
        const float mu = s1 * (1.f / 256.f);
        const float var = s2 * (1.f / 256.f) - mu * mu;
        const float rs = rsqrtf(var + 1e-5f);
        const int gm = m0 + rl;
        if (gm < M) {
          const size_t base = (size_t)gm * 256 + wn + (lane & 15);
#pragma unroll
          for (int j = 0; j < 4; ++j)
            C[base + j * 16] = f2bf((acc[i][j][r] - mu) * rs * gv[j] + bv[j]);
        }
      }
    }
  } else {
#pragma unroll
    for (int i = 0; i < 4; ++i) {
      const int gm0 = m0 + i * 16 + ((lane >> 4) << 2);
#pragma unroll
      for (int r = 0; r < 4; ++r) {
        const int gm = gm0 + r;
        if (gm < M) {
          const size_t base = (size_t)gm * 256 + wn + (lane & 15);
#pragma unroll
          for (int j = 0; j < 4; ++j) {
            float v = acc[i][j][r] + bi[j];
            if (ADDZ) v += bf2f(Z[base + j * 16]);
            if (RELU) v = fmaxf(v, 0.f);
            C[base + j * 16] = f2bf(v);
          }
        }
      }
    }
  }
}

// ---------------------------------------------------------------------------
// Fold: outp (+)= sum_{k<P} betas[l0+k] * bf2f(zbase[k][i]); 8 elems/thread.
// ---------------------------------------------------------------------------
template <int WRITE>
__global__ __launch_bounds__(256) void fold_kernel(
    const ushort* __restrict__ zbase, size_t ZS, const float* __restrict__ betas,
    int l0, int P, float* __restrict__ outp, int total8) {
  const int i = blockIdx.x * 256 + threadIdx.x;
  if (i >= total8) return;
  float a[8] = {};
  for (int k = 0; k < P; ++k) {
    const float bl = betas[l0 + k];
    const uint4 u = ((const uint4*)(zbase + k * ZS))[i];
    const uint32_t ww[4] = {u.x, u.y, u.z, u.w};
#pragma unroll
    for (int q = 0; q < 4; ++q) {
      union { uint32_t u; float f; } lo, hi;
      lo.u = ww[q] << 16;
      hi.u = ww[q] & 0xffff0000u;
      a[2 * q] += bl * lo.f;
      a[2 * q + 1] += bl * hi.f;
    }
  }
  f32x4 o0 = {a[0], a[1], a[2], a[3]};
  f32x4 o1 = {a[4], a[5], a[6], a[7]};
  if (WRITE) {
    ((f32x4*)outp)[(size_t)i * 2] = o0;
    ((f32x4*)outp)[(size_t)i * 2 + 1] = o1;
  } else {
    f32x4 p0 = ((f32x4*)outp)[(size_t)i * 2];
    f32x4 p1 = ((f32x4*)outp)[(size_t)i * 2 + 1];
    ((f32x4*)outp)[(size_t)i * 2] = p0 + o0;
    ((f32x4*)outp)[(size_t)i * 2 + 1] = p1 + o1;
  }
}

// ---------------------------------------------------------------------------
// CSR build (parallel scan), 1 edge/thread (4x unroll regressed: r10)
// ---------------------------------------------------------------------------
__global__ void count_kernel(const int* __restrict__ dstv, int* __restrict__ deg, int E) {
  int i = blockIdx.x * 256 + threadIdx.x;
  if (i < E) atomicAdd(&deg[dstv[i]], 1);
}

__global__ void scanA_kernel(const int* __restrict__ deg, int* __restrict__ excl,
                             int* __restrict__ bsum, int n) {
  __shared__ int sm[256];
  const int i = blockIdx.x * 256 + threadIdx.x;
  const int v = (i < n) ? deg[i] : 0;
  sm[threadIdx.x] = v;
  __syncthreads();
  for (int off = 1; off < 256; off <<= 1) {
    int t = (threadIdx.x >= off) ? sm[threadIdx.x - off] : 0;
    __syncthreads();
    sm[threadIdx.x] += t;
    __syncthreads();
  }
  if (i < n) excl[i] = sm[threadIdx.x] - v;
  if (threadIdx.x == 255) bsum[blockIdx.x] = sm[255];
}

__global__ void scanB_kernel(const int* __restrict__ bsum, int* __restrict__ boff, int nb) {
  __shared__ int sm[256];
  const int v = (threadIdx.x < nb) ? bsum[threadIdx.x] : 0;
  sm[threadIdx.x] = v;
  __syncthreads();
  for (int off = 1; off < 256; off <<= 1) {
    int t = (threadIdx.x >= off) ? sm[threadIdx.x - off] : 0;
    __syncthreads();
    sm[threadIdx.x] += t;
    __syncthreads();
  }
  if (threadIdx.x < nb) boff[threadIdx.x] = sm[threadIdx.x] - v;
}

__global__ void scanC_kernel(const int* __restrict__ deg, const int* __restrict__ excl,
                             const int* __restrict__ boff, int* __restrict__ rowptr,
                             int* __restrict__ fillptr, float* __restrict__ invc,
                             int n, int E) {
  const int i = blockIdx.x * 256 + threadIdx.x;
  if (i < n) {
    const int r = excl[i] + boff[blockIdx.x];
    rowptr[i] = r;
    fillptr[i] = r;
    invc[i] = 1.0f / (float)(deg[i] + 1);
  }
  if (i == 0) rowptr[n] = E;
}

__global__ void fill_kernel(const int* __restrict__ srcv, const int* __restrict__ dstv,
                            int* __restrict__ fillptr, int* __restrict__ colv, int E) {
  int i = blockIdx.x * 256 + threadIdx.x;
  if (i < E) {
    int p = atomicAdd(&fillptr[dstv[i]], 1);
    colv[p] = srcv[i];
  }
}

// ---------------------------------------------------------------------------
// 128-d aggregation, quarter-wave (16 lanes x 16B) per node, x4 unroll.
// ---------------------------------------------------------------------------
__global__ __launch_bounds__(256) void agg128_kernel(
    const ushort* __restrict__ T, const int* __restrict__ rowptr,
    const int* __restrict__ colv, const float* __restrict__ invc,
    ushort* __restrict__ sout, int n) {
  const int node = blockIdx.x * 16 + (threadIdx.x >> 4);
  if (node >= n) return;
  const int q = threadIdx.x & 15;
  const uint4* Tv = (const uint4*)T;  // row = 16 x 16B chunks
  float a[8] = {}, b[8] = {}, c[8] = {}, d[8] = {};
  auto addu = [](float* acc, uint4 u) {
    const uint32_t ww[4] = {u.x, u.y, u.z, u.w};
#pragma unroll
    for (int k = 0; k < 4; ++k) {
      union { uint32_t u; float f; } lo, hi;
      lo.u = ww[k] << 16;
      hi.u = ww[k] & 0xffff0000u;
      acc[2 * k] += lo.f;
      acc[2 * k + 1] += hi.f;
    }
  };
  addu(a, Tv[(size_t)node * 16 + q]);
  const int s = rowptr[node];
  const int e = rowptr[node + 1];
  int i = s;
  for (; i + 3 < e; i += 4) {
    const uint4 u0 = Tv[(size_t)colv[i] * 16 + q];
    const uint4 u1 = Tv[(size_t)colv[i + 1] * 16 + q];
    const uint4 u2 = Tv[(size_t)colv[i + 2] * 16 + q];
    const uint4 u3 = Tv[(size_t)colv[i + 3] * 16 + q];
    addu(a, u0);
    addu(b, u1);
    addu(c, u2);
    addu(d, u3);
  }
  for (; i < e; ++i) addu(a, Tv[(size_t)colv[i] * 16 + q]);
  const float ic = invc[node];
  uint4 o;
  uint32_t* ow = (uint32_t*)&o;
#pragma unroll
  for (int k = 0; k < 4; ++k) {
    const float r0 = (a[2 * k] + b[2 * k] + c[2 * k] + d[2 * k]) * ic;
    const float r1 = (a[2 * k + 1] + b[2 * k + 1] + c[2 * k + 1] + d[2 * k + 1]) * ic;
    ow[k] = (uint32_t)f2bf(r0) | ((uint32_t)f2bf(r1) << 16);
  }
  ((uint4*)sout)[(size_t)node * 16 + q] = o;
}

__global__ void beta_kernel(const float* __restrict__ beta, float* __restrict__ betas) {
  if (threadIdx.x == 0) {
    float mx = beta[0];
    for (int i = 1; i < NLAYER + 1; ++i) mx = fmaxf(mx, beta[i]);
    float e[NLAYER + 1];
    float s = 0.f;
    for (int i = 0; i < NLAYER + 1; ++i) {
      e[i] = expf(beta[i] - mx);
      s += e[i];
    }
    const float inv = 1.f / s;
    for (int i = 0; i < NLAYER + 1; ++i) betas[i] = e[i] * inv;
  }
}

// W[K][N] f32 -> Wt[N][K] bf16
__global__ void wconv_kernel(const float* __restrict__ W, ushort* __restrict__ Wt,
                             int K, int Nn) {
  const size_t matoff = (size_t)blockIdx.z * K * Nn;
  const int o = blockIdx.x * 256 + threadIdx.x;
  if (o >= K * Nn) return;
  const int nn = o / K;
  const int kk = o - nn * K;
  Wt[matoff + o] = f2bf(W[matoff + (size_t)kk * Nn + nn]);
}

// U1 and U2 (both [L][256][256]) in one launch
__global__ void wconvU_kernel(const float* __restrict__ U1, const float* __restrict__ U2,
                              ushort* __restrict__ U1T, ushort* __restrict__ U2T) {
  const int li = blockIdx.z;
  const float* W = (li < NLAYER) ? U1 : U2;
  ushort* Wt = (li < NLAYER) ? U1T : U2T;
  const size_t matoff = (size_t)(li % NLAYER) * 256 * 256;
  const int o = blockIdx.x * 256 + threadIdx.x;
  const int nn = o >> 8;
  const int kk = o & 255;
  Wt[matoff + o] = f2bf(W[matoff + (size_t)kk * 256 + nn]);
}

// x f32 -> bf16, 8/thread
__global__ void xcast_kernel(const float* __restrict__ x, ushort* __restrict__ xb, int n8) {
  const int i = blockIdx.x * 256 + threadIdx.x;
  if (i >= n8) return;
  const f32x4 v0 = ((const f32x4*)x)[(size_t)i * 2];
  const f32x4 v1 = ((const f32x4*)x)[(size_t)i * 2 + 1];
  bf16x8 o;
#pragma unroll
  for (int q = 0; q < 4; ++q) {
    o[q] = (short)f2bf(v0[q]);
    o[q + 4] = (short)f2bf(v1[q]);
  }
  *(bf16x8*)(xb + (size_t)i * 8) = o;
}

// Win GEMM (z0): A bf16 [M x 128], B bf16 [256 x 128], C bf16 [M x 256].
__global__ __launch_bounds__(512, 4) void gemm_win(
    const ushort* __restrict__ A, const ushort* __restrict__ B,
    const float* __restrict__ bias, ushort* __restrict__ C, int M) {
  __shared__ ushort lA[128 * 64];
  __shared__ ushort lB[256 * 64];
  const int tid = threadIdx.x;
  const int m0 = blockIdx.x * 128;
  const int lane = tid & 63;
  const int w = tid >> 6;
  const int wm = (w >> 2) * 64;
  const int wn = (w & 3) * 64;
  const int rr = tid >> 3;
  const int cc = tid & 7;
  f32x4 acc[4][4] = {};
  const int K = 128;

#pragma unroll
  for (int s = 0; s < 2; ++s) {
    const int k0 = s * 64;
#pragma unroll
    for (int p = 0; p < 2; ++p) {
      const int row = p * 64 + rr;
      const int gm = m0 + row;
      bf16x8 av = {0, 0, 0, 0, 0, 0, 0, 0};
      if (gm < M) av = *(const bf16x8*)(A + (size_t)gm * K + k0 + cc * 8);
      const uint32_t off = (uint32_t)((row * 128 + cc * 16) ^ ((row & 7) << 4));
      *(bf16x8*)((char*)lA + off) = av;
    }
#pragma unroll
    for (int p = 0; p < 4; ++p) {
      const int row = p * 64 + rr;
      bf16x8 bv = *(const bf16x8*)(B + (size_t)row * K + k0 + cc * 8);
      const uint32_t off = (uint32_t)((row * 128 + cc * 16) ^ ((row & 7) << 4));
      *(bf16x8*)((char*)lB + off) = bv;
    }
    __syncthreads();
#pragma unroll
    for (int kk = 0; kk < 2; ++kk) {
      bf16x8 ah[4];
#pragma unroll
      for (int i = 0; i < 4; ++i) {
        const int arow = wm + i * 16 + (lane & 15);
        const uint32_t ao =
            (uint32_t)((arow * 128 + kk * 64 + ((lane >> 4) * 16)) ^ ((arow & 7) << 4));
        ah[i] = *(const bf16x8*)((const char*)lA + ao);
      }
#pragma unroll
      for (int j = 0; j < 4; ++j) {
        const int brow = wn + j * 16 + (lane & 15);
        const uint32_t bo =
            (uint32_t)((brow * 128 + kk * 64 + ((lane >> 4) * 16)) ^ ((brow & 7) << 4));
        const bf16x8 bv = *(const bf16x8*)((const char*)lB + bo);
#pragma unroll
        for (int i = 0; i < 4; ++i)
          acc[i][j] = __builtin_amdgcn_mfma_f32_16x16x32_bf16(ah[i], bv, acc[i][j], 0, 0, 0);
      }
    }
    __syncthreads();
  }
  float bi[4];
#pragma unroll
  for (int j = 0; j < 4; ++j) bi[j] = bias[wn + j * 16 + (lane & 15)];
#pragma unroll
  for (int i = 0; i < 4; ++i) {
    const int gm0 = m0 + wm + i * 16 + ((lane >> 4) << 2);
#pragma unroll
    for (int r = 0; r < 4; ++r) {
      const int gm = gm0 + r;
      if (gm < M) {
        const size_t base = (size_t)gm * 256 + wn + (lane & 15);
#pragma unroll
        for (int j = 0; j < 4; ++j)
          C[base + j * 16] = f2bf(acc[i][j][r] + bi[j]);
      }
    }
  }
}

// ---------------------------------------------------------------------------
extern "C" void kernel_launch(void* const* d_in, const int* in_sizes, int n_in,
                              void* d_out, int out_size, void* d_ws, size_t ws_size,
                              hipStream_t stream) {
  const float* x = (const float*)d_in[0];
  const int* eidx = (const int*)d_in[1];
  const float* Win = (const float*)d_in[2];
  const float* bin_ = (const float*)d_in[3];
  const float* W1 = (const float*)d_in[4];
  const float* b1 = (const float*)d_in[5];
  const float* W2 = (const float*)d_in[6];
  const float* b2 = (const float*)d_in[7];
  const float* U1 = (const float*)d_in[8];
  const float* c1 = (const float*)d_in[9];
  const float* U2 = (const float*)d_in[10];
  const float* c2 = (const float*)d_in[11];
  const float* ln_g = (const float*)d_in[12];
  const float* ln_b = (const float*)d_in[13];
  const float* beta = (const float*)d_in[14];
  float* outp = (float*)d_out;

  const int Nn = in_sizes[0] / 128;  // 50000
  const int E = in_sizes[1] / 2;     // 800000
  const int* srcv = eidx;
  const int* dstv = eidx + E;

  char* p = (char*)d_ws;
  auto alloc = [&](size_t bytes) {
    char* r = p;
    p += (bytes + 255) & ~(size_t)255;
    return r;
  };
  ushort* hbuf = (ushort*)alloc((size_t)Nn * HIDC * 2);  // h bf16
  ushort* TSO = (ushort*)alloc((size_t)Nn * HIDC * 2);   // T | s, later O
  ushort* xbf = (ushort*)alloc((size_t)Nn * 128 * 2);
  ushort* WinT = (ushort*)alloc(128 * 256 * 2);
  ushort* W1T = (ushort*)alloc((size_t)NLAYER * 256 * 128 * 2);
  ushort* W2T = (ushort*)alloc((size_t)NLAYER * 128 * 256 * 2);
  ushort* U1T = (ushort*)alloc((size_t)NLAYER * 256 * 256 * 2);
  ushort* U2T = (ushort*)alloc((size_t)NLAYER * 256 * 256 * 2);
  int* deg = (int*)alloc((size_t)Nn * 4);
  int* rowptr = (int*)alloc((size_t)(Nn + 1) * 4);
  int* fillptr = (int*)alloc((size_t)Nn * 4);
  float* invc = (float*)alloc((size_t)Nn * 4);
  int* colv = (int*)alloc((size_t)E * 4);
  int* excl = (int*)alloc((size_t)Nn * 4);
  int* bsum = (int*)alloc(256 * 4);
  int* boff = (int*)alloc(256 * 4);
  float* betas = (float*)alloc(64);

  // z-history slots: as many as fit (G in [2, 11])
  const size_t ZS = (size_t)Nn * HIDC;
  const size_t slotB = ZS * 2;
  const size_t used = (size_t)(p - (char*)d_ws);
  int G = 2;
  if (ws_size > used + 4096) {
    size_t fit = (ws_size - used - 4096) / (slotB + 256);
    G = (int)(fit < 2 ? 2 : (fit > NLAYER + 1 ? NLAYER + 1 : fit));
  }
  ushort* zbase = (ushort*)alloc((size_t)G * slotB);

  ushort* T128 = TSO;
  ushort* s128 = TSO + (size_t)Nn * MSGC;
  ushort* Obuf = TSO;  // reuses T|s after both consumed

  const int nscan = (Nn + 255) / 256;
  const int mb128 = (Nn + 127) / 128;
  const int mb64 = (Nn + 63) / 64;
  const int nagg = (Nn + 15) / 16;
  const int total8 = (Nn * HIDC) / 8;

  hipMemsetAsync(deg, 0, (size_t)Nn * 4, stream);
  count_kernel<<<(E + 255) / 256, 256, 0, stream>>>(dstv, deg, E);
  scanA_kernel<<<nscan, 256, 0, stream>>>(deg, excl, bsum, Nn);
  scanB_kernel<<<1, 256, 0, stream>>>(bsum, boff, nscan);
  scanC_kernel<<<nscan, 256, 0, stream>>>(deg, excl, boff, rowptr, fillptr, invc, Nn, E);
  fill_kernel<<<(E + 255) / 256, 256, 0, stream>>>(srcv, dstv, fillptr, colv, E);
  beta_kernel<<<1, 64, 0, stream>>>(beta, betas);
  xcast_kernel<<<(Nn * 16 + 255) / 256, 256, 0, stream>>>(x, xbf, Nn * 16);
  wconv_kernel<<<dim3(128, 1, 1), 256, 0, stream>>>(Win, WinT, 128, 256);
  wconv_kernel<<<dim3(128, 1, NLAYER), 256, 0, stream>>>(W1, W1T, 256, 128);
  wconv_kernel<<<dim3(128, 1, NLAYER), 256, 0, stream>>>(W2, W2T, 128, 256);
  wconvU_kernel<<<dim3(256, 1, 2 * NLAYER), 256, 0, stream>>>(U1, U2, U1T, U2T);

  // fold bookkeeping
  int pend = 0, l0 = 0;
  bool first = true;
  auto flush = [&]() {
    if (pend > 0) {
      if (first)
        fold_kernel<1><<<(total8 + 255) / 256, 256, 0, stream>>>(zbase, ZS, betas, l0,
                                                                 pend, outp, total8);
      else
        fold_kernel<0><<<(total8 + 255) / 256, 256, 0, stream>>>(zbase, ZS, betas, l0,
                                                                 pend, outp, total8);
      first = false;
      l0 += pend;
      pend = 0;
    }
  };

  // z0 = x @ Win + bin -> slot 0
  ushort* zcur = zbase;
  gemm_win<<<mb128, 512, 0, stream>>>(xbf, WinT, bin_, zcur, Nn);
  pend = 1;

  for (int l = 0; l < NLAYER; ++l) {
    // T = bf16(relu(z @ W1 + b1))
    gemm_w1_64<<<mb64, 256, 0, stream>>>(zcur, W1T + (size_t)l * 256 * 128,
                                         b1 + l * 128, T128, Nn);
    // s = bf16(segmean(T))
    agg128_kernel<<<nagg, 256, 0, stream>>>(T128, rowptr, colv, invc, s128, Nn);
    // h = bf16(z + s @ W2 + b2)
    gemm_big64<0, 1, 0><<<mb64, 256, 0, stream>>>(s128, W2T + (size_t)l * 128 * 256,
                                                  b2 + l * 256, zcur, hbuf, nullptr,
                                                  nullptr, Nn, 128);
    // O = bf16(relu(h @ U1 + c1))
    gemm_big64<1, 0, 0><<<mb64, 256, 0, stream>>>(hbuf, U1T + (size_t)l * 256 * 256,
                                                  c1 + l * 256, nullptr, Obuf, nullptr,
                                                  nullptr, Nn, 256);
    // fold if all slots full
    if (pend == G) flush();
    // z' = bf16(LN(O @ U2 + c2)*g + b)
    ushort* znext = zbase + (size_t)pend * ZS;
    gemm_big64<0, 0, 1><<<mb64, 256, 0, stream>>>(Obuf, U2T + (size_t)l * 256 * 256,
                                                  c2 + l * 256, nullptr, znext,
                                                  ln_g + l * 256, ln_b + l * 256, Nn, 256);
    zcur = znext;
    pend++;
  }
  flush();
}

// Round 12
// 1261.283 us; speedup vs baseline: 1.1631x; 1.0203x over previous
//
#include <hip/hip_runtime.h>
#include <stdint.h>

typedef __attribute__((ext_vector_type(4))) float f32x4;
typedef __attribute__((ext_vector_type(8))) short bf16x8;

#define HIDC 256
#define MSGC 128
#define NLAYER 10

__device__ __forceinline__ ushort f2bf(float f) {
  union { float f; uint32_t u; } a; a.f = f;
  uint32_t u = a.u;
  return (ushort)((u + 0x7fffu + ((u >> 16) & 1u)) >> 16);
}
__device__ __forceinline__ float bf2f(ushort h) {
  union { float f; uint32_t u; } a; a.u = ((uint32_t)h) << 16;
  return a.f;
}

// async global->LDS, 16B per lane; dst must be wave-uniform base (lane*16 added by HW)
__device__ __forceinline__ void gll16(const void* g, void* l) {
  __builtin_amdgcn_global_load_lds(
      (const __attribute__((address_space(1))) void*)g,
      (__attribute__((address_space(3))) void*)l, 16, 0, 0);
}

// ---------------------------------------------------------------------------
// W1 GEMM: A bf16 [M x 256], B bf16 [128 x 256](T), C bf16 [M x 128].
// Tile 64x128, 4 waves, BK=64, RELU fused. Staging via global_load_lds with
// pre-swizzled source column (linear LDS dest == swizzled content).
// ---------------------------------------------------------------------------
__global__ __launch_bounds__(256, 4) void gemm_w1_64(
    const ushort* __restrict__ A, const ushort* __restrict__ B,
    const float* __restrict__ bias, ushort* __restrict__ C, int M) {
  __shared__ ushort lA[64 * 64];
  __shared__ ushort lB[128 * 64];
  const int tid = threadIdx.x;
  const int m0 = blockIdx.x * 64;
  const int lane = tid & 63;
  const int w = tid >> 6;
  const int wm = (w >> 1) * 32;  // 0,32
  const int wn = (w & 1) * 64;   // 0,64
  const int rr = tid >> 3;       // 0..31 (= w*8 + (lane>>3))
  const int cc = tid & 7;        // 0..7
  const int ccs = cc ^ (rr & 7); // pre-swizzled source chunk
  const bool full = (m0 + 64 <= M);
  f32x4 acc[2][4] = {};

#pragma unroll
  for (int s = 0; s < 4; ++s) {  // K = 256
    const int k0 = s * 64;
    if (full) {
#pragma unroll
      for (int p = 0; p < 2; ++p) {
        const int row = p * 32 + rr;
        gll16(A + (size_t)(m0 + row) * 256 + k0 + ccs * 8,
              lA + (size_t)(p * 32 + w * 8) * 64);
      }
    } else {
#pragma unroll
      for (int p = 0; p < 2; ++p) {
        const int row = p * 32 + rr;
        const int gm = m0 + row;
        bf16x8 av = {0, 0, 0, 0, 0, 0, 0, 0};
        if (gm < M) av = *(const bf16x8*)(A + (size_t)gm * 256 + k0 + cc * 8);
        const uint32_t off = (uint32_t)((row * 128 + cc * 16) ^ ((row & 7) << 4));
        *(bf16x8*)((char*)lA + off) = av;
      }
    }
#pragma unroll
    for (int p = 0; p < 4; ++p) {
      const int row = p * 32 + rr;
      gll16(B + (size_t)row * 256 + k0 + ccs * 8,
            lB + (size_t)(p * 32 + w * 8) * 64);
    }
    __syncthreads();
#pragma unroll
    for (int kk = 0; kk < 2; ++kk) {
      bf16x8 ah[2];
#pragma unroll
      for (int i = 0; i < 2; ++i) {
        const int arow = wm + i * 16 + (lane & 15);
        const uint32_t ao =
            (uint32_t)((arow * 128 + kk * 64 + ((lane >> 4) * 16)) ^ ((arow & 7) << 4));
        ah[i] = *(const bf16x8*)((const char*)lA + ao);
      }
#pragma unroll
      for (int j = 0; j < 4; ++j) {
        const int brow = wn + j * 16 + (lane & 15);
        const uint32_t bo =
            (uint32_t)((brow * 128 + kk * 64 + ((lane >> 4) * 16)) ^ ((brow & 7) << 4));
        const bf16x8 bv = *(const bf16x8*)((const char*)lB + bo);
#pragma unroll
        for (int i = 0; i < 2; ++i)
          acc[i][j] = __builtin_amdgcn_mfma_f32_16x16x32_bf16(ah[i], bv, acc[i][j], 0, 0, 0);
      }
    }
    __syncthreads();
  }
  float bi[4];
#pragma unroll
  for (int j = 0; j < 4; ++j) bi[j] = bias[wn + j * 16 + (lane & 15)];
#pragma unroll
  for (int i = 0; i < 2; ++i) {
    const int gm0 = m0 + wm + i * 16 + ((lane >> 4) << 2);
#pragma unroll
    for (int r = 0; r < 4; ++r) {
      const int gm = gm0 + r;
      if (gm < M) {
        const size_t base = (size_t)gm * 128 + wn + (lane & 15);
#pragma unroll
        for (int j = 0; j < 4; ++j)
          C[base + j * 16] = f2bf(fmaxf(acc[i][j][r] + bi[j], 0.f));
      }
    }
  }
}

// ---------------------------------------------------------------------------
// Big GEMM 64-row: A bf16 [M x K], B bf16 [256 x K], tile 64x256, 4 waves.
// LN=0: C = bf16(act(A@B^T + bias [+Z]))
// LN=1: C = bf16(LN(A@B^T + bias)*g + b_)
// ---------------------------------------------------------------------------
template <int RELU, int ADDZ, int LN>
__global__ __launch_bounds__(256, 3) void gemm_big64(
    const ushort* __restrict__ A, const ushort* __restrict__ B,
    const float* __restrict__ bias, const ushort* __restrict__ Z,
    ushort* __restrict__ C, const float* __restrict__ g,
    const float* __restrict__ b_, int M, int K) {
  __shared__ ushort lA[64 * 64];
  __shared__ ushort lB[256 * 64];
  __shared__ float sstat[2][4][64];
  const int tid = threadIdx.x;
  const int m0 = blockIdx.x * 64;
  const int lane = tid & 63;
  const int w = tid >> 6;      // 0..3
  const int wn = w * 64;       // col slice per wave
  const int rr = tid >> 3;     // 0..31
  const int cc = tid & 7;      // 0..7
  const int ccs = cc ^ (rr & 7);
  const bool full = (m0 + 64 <= M);
  f32x4 acc[4][4] = {};

  const int nsteps = K >> 6;
  for (int s = 0; s < nsteps; ++s) {
    const int k0 = s * 64;
    if (full) {
#pragma unroll
      for (int p = 0; p < 2; ++p) {
        const int row = p * 32 + rr;
        gll16(A + (size_t)(m0 + row) * K + k0 + ccs * 8,
              lA + (size_t)(p * 32 + w * 8) * 64);
      }
    } else {
#pragma unroll
      for (int p = 0; p < 2; ++p) {
        const int row = p * 32 + rr;
        const int gm = m0 + row;
        bf16x8 av = {0, 0, 0, 0, 0, 0, 0, 0};
        if (gm < M) av = *(const bf16x8*)(A + (size_t)gm * K + k0 + cc * 8);
        const uint32_t off = (uint32_t)((row * 128 + cc * 16) ^ ((row & 7) << 4));
        *(bf16x8*)((char*)lA + off) = av;
      }
    }
#pragma unroll
    for (int p = 0; p < 8; ++p) {
      const int row = p * 32 + rr;
      gll16(B + (size_t)row * K + k0 + ccs * 8,
            lB + (size_t)(p * 32 + w * 8) * 64);
    }
    __syncthreads();
#pragma unroll
    for (int kk = 0; kk < 2; ++kk) {
      bf16x8 ah[4];
#pragma unroll
      for (int i = 0; i < 4; ++i) {
        const int arow = i * 16 + (lane & 15);
        const uint32_t ao =
            (uint32_t)((arow * 128 + kk * 64 + ((lane >> 4) * 16)) ^ ((arow & 7) << 4));
        ah[i] = *(const bf16x8*)((const char*)lA + ao);
      }
#pragma unroll
      for (int j = 0; j < 4; ++j) {
        const int brow = wn + j * 16 + (lane & 15);
        const uint32_t bo =
            (uint32_t)((brow * 128 + kk * 64 + ((lane >> 4) * 16)) ^ ((brow & 7) << 4));
        const bf16x8 bv = *(const bf16x8*)((const char*)lB + bo);
#pragma unroll
        for (int i = 0; i < 4; ++i)
          acc[i][j] = __builtin_amdgcn_mfma_f32_16x16x32_bf16(ah[i], bv, acc[i][j], 0, 0, 0);
      }
    }
    __syncthreads();
  }

  float bi[4];
#pragma unroll
  for (int j = 0; j < 4; ++j) bi[j] = bias[wn + j * 16 + (lane & 15)];

  if (LN) {
    float gv[4], bv[4];
#pragma unroll
    for (int j = 0; j < 4; ++j) {
      gv[j] = g[wn + j * 16 + (lane & 15)];
      bv[j] = b_[wn + j * 16 + (lane & 15)];
    }
#pragma unroll
    for (int i = 0; i < 4; ++i) {
#pragma unroll
      for (int r = 0; r < 4; ++r) {
        float s1 = 0.f, s2 = 0.f;
#pragma unroll
        for (int j = 0; j < 4; ++j) {
          float v = acc[i][j][r] + bi[j];
          acc[i][j][r] = v;
          s1 += v;
          s2 += v * v;
        }
#pragma unroll
        for (int d = 1; d < 16; d <<= 1) {
          s1 += __shfl_xor(s1, d);
          s2 += __shfl_xor(s2, d);
        }
        if ((lane & 15) == 0) {
          const int rl = i * 16 + ((lane >> 4) << 2) + r;
          sstat[0][w][rl] = s1;
          sstat[1][w][rl] = s2;
        }
      }
    }
    __syncthreads();
#pragma unroll
    for (int i = 0; i < 4; ++i) {
#pragma unroll
      for (int r = 0; r < 4; ++r) {
        const int rl = i * 16 + ((lane >> 4) << 2) + r;
        const float s1 = sstat[0][0][rl] + sstat[0][1][rl] + sstat[0][2][rl] + sstat[0][3][rl];
        const float s2 = sstat[1][0][rl] + sstat[1][1][rl] + sstat[1][2][rl] + sstat[1][3][rl];
        const float mu = s1 * (1.f / 256.f);
        const float var = s2 * (1.f / 256.f) - mu * mu;
        const float rs = rsqrtf(var + 1e-5f);
        const int gm = m0 + rl;
        if (gm < M) {
          const size_t base = (size_t)gm * 256 + wn + (lane & 15);
#pragma unroll
          for (int j = 0; j < 4; ++j)
            C[base + j * 16] = f2bf((acc[i][j][r] - mu) * rs * gv[j] + bv[j]);
        }
      }
    }
  } else {
#pragma unroll
    for (int i = 0; i < 4; ++i) {
      const int gm0 = m0 + i * 16 + ((lane >> 4) << 2);
#pragma unroll
      for (int r = 0; r < 4; ++r) {
        const int gm = gm0 + r;
        if (gm < M) {
          const size_t base = (size_t)gm * 256 + wn + (lane & 15);
#pragma unroll
          for (int j = 0; j < 4; ++j) {
            float v = acc[i][j][r] + bi[j];
            if (ADDZ) v += bf2f(Z[base + j * 16]);
            if (RELU) v = fmaxf(v, 0.f);
            C[base + j * 16] = f2bf(v);
          }
        }
      }
    }
  }
}

// ---------------------------------------------------------------------------
// Fold: outp (+)= sum_{k<P} betas[l0+k] * bf2f(zbase[k][i]); 8 elems/thread.
// ---------------------------------------------------------------------------
template <int WRITE>
__global__ __launch_bounds__(256) void fold_kernel(
    const ushort* __restrict__ zbase, size_t ZS, const float* __restrict__ betas,
    int l0, int P, float* __restrict__ outp, int total8) {
  const int i = blockIdx.x * 256 + threadIdx.x;
  if (i >= total8) return;
  float a[8] = {};
  for (int k = 0; k < P; ++k) {
    const float bl = betas[l0 + k];
    const uint4 u = ((const uint4*)(zbase + k * ZS))[i];
    const uint32_t ww[4] = {u.x, u.y, u.z, u.w};
#pragma unroll
    for (int q = 0; q < 4; ++q) {
      union { uint32_t u; float f; } lo, hi;
      lo.u = ww[q] << 16;
      hi.u = ww[q] & 0xffff0000u;
      a[2 * q] += bl * lo.f;
      a[2 * q + 1] += bl * hi.f;
    }
  }
  f32x4 o0 = {a[0], a[1], a[2], a[3]};
  f32x4 o1 = {a[4], a[5], a[6], a[7]};
  if (WRITE) {
    ((f32x4*)outp)[(size_t)i * 2] = o0;
    ((f32x4*)outp)[(size_t)i * 2 + 1] = o1;
  } else {
    f32x4 p0 = ((f32x4*)outp)[(size_t)i * 2];
    f32x4 p1 = ((f32x4*)outp)[(size_t)i * 2 + 1];
    ((f32x4*)outp)[(size_t)i * 2] = p0 + o0;
    ((f32x4*)outp)[(size_t)i * 2 + 1] = p1 + o1;
  }
}

// ---------------------------------------------------------------------------
// CSR build (parallel scan), 1 edge/thread
// ---------------------------------------------------------------------------
__global__ void count_kernel(const int* __restrict__ dstv, int* __restrict__ deg, int E) {
  int i = blockIdx.x * 256 + threadIdx.x;
  if (i < E) atomicAdd(&deg[dstv[i]], 1);
}

__global__ void scanA_kernel(const int* __restrict__ deg, int* __restrict__ excl,
                             int* __restrict__ bsum, int n) {
  __shared__ int sm[256];
  const int i = blockIdx.x * 256 + threadIdx.x;
  const int v = (i < n) ? deg[i] : 0;
  sm[threadIdx.x] = v;
  __syncthreads();
  for (int off = 1; off < 256; off <<= 1) {
    int t = (threadIdx.x >= off) ? sm[threadIdx.x - off] : 0;
    __syncthreads();
    sm[threadIdx.x] += t;
    __syncthreads();
  }
  if (i < n) excl[i] = sm[threadIdx.x] - v;
  if (threadIdx.x == 255) bsum[blockIdx.x] = sm[255];
}

__global__ void scanB_kernel(const int* __restrict__ bsum, int* __restrict__ boff, int nb) {
  __shared__ int sm[256];
  const int v = (threadIdx.x < nb) ? bsum[threadIdx.x] : 0;
  sm[threadIdx.x] = v;
  __syncthreads();
  for (int off = 1; off < 256; off <<= 1) {
    int t = (threadIdx.x >= off) ? sm[threadIdx.x - off] : 0;
    __syncthreads();
    sm[threadIdx.x] += t;
    __syncthreads();
  }
  if (threadIdx.x < nb) boff[threadIdx.x] = sm[threadIdx.x] - v;
}

__global__ void scanC_kernel(const int* __restrict__ deg, const int* __restrict__ excl,
                             const int* __restrict__ boff, int* __restrict__ rowptr,
                             int* __restrict__ fillptr, float* __restrict__ invc,
                             int n, int E) {
  const int i = blockIdx.x * 256 + threadIdx.x;
  if (i < n) {
    const int r = excl[i] + boff[blockIdx.x];
    rowptr[i] = r;
    fillptr[i] = r;
    invc[i] = 1.0f / (float)(deg[i] + 1);
  }
  if (i == 0) rowptr[n] = E;
}

__global__ void fill_kernel(const int* __restrict__ srcv, const int* __restrict__ dstv,
                            int* __restrict__ fillptr, int* __restrict__ colv, int E) {
  int i = blockIdx.x * 256 + threadIdx.x;
  if (i < E) {
    int p = atomicAdd(&fillptr[dstv[i]], 1);
    colv[p] = srcv[i];
  }
}

// ---------------------------------------------------------------------------
// 128-d aggregation, quarter-wave (16 lanes x 16B) per node, x4 unroll.
// ---------------------------------------------------------------------------
__global__ __launch_bounds__(256) void agg128_kernel(
    const ushort* __restrict__ T, const int* __restrict__ rowptr,
    const int* __restrict__ colv, const float* __restrict__ invc,
    ushort* __restrict__ sout, int n) {
  const int node = blockIdx.x * 16 + (threadIdx.x >> 4);
  if (node >= n) return;
  const int q = threadIdx.x & 15;
  const uint4* Tv = (const uint4*)T;  // row = 16 x 16B chunks
  float a[8] = {}, b[8] = {}, c[8] = {}, d[8] = {};
  auto addu = [](float* acc, uint4 u) {
    const uint32_t ww[4] = {u.x, u.y, u.z, u.w};
#pragma unroll
    for (int k = 0; k < 4; ++k) {
      union { uint32_t u; float f; } lo, hi;
      lo.u = ww[k] << 16;
      hi.u = ww[k] & 0xffff0000u;
      acc[2 * k] += lo.f;
      acc[2 * k + 1] += hi.f;
    }
  };
  addu(a, Tv[(size_t)node * 16 + q]);
  const int s = rowptr[node];
  const int e = rowptr[node + 1];
  int i = s;
  for (; i + 3 < e; i += 4) {
    const uint4 u0 = Tv[(size_t)colv[i] * 16 + q];
    const uint4 u1 = Tv[(size_t)colv[i + 1] * 16 + q];
    const uint4 u2 = Tv[(size_t)colv[i + 2] * 16 + q];
    const uint4 u3 = Tv[(size_t)colv[i + 3] * 16 + q];
    addu(a, u0);
    addu(b, u1);
    addu(c, u2);
    addu(d, u3);
  }
  for (; i < e; ++i) addu(a, Tv[(size_t)colv[i] * 16 + q]);
  const float ic = invc[node];
  uint4 o;
  uint32_t* ow = (uint32_t*)&o;
#pragma unroll
  for (int k = 0; k < 4; ++k) {
    const float r0 = (a[2 * k] + b[2 * k] + c[2 * k] + d[2 * k]) * ic;
    const float r1 = (a[2 * k + 1] + b[2 * k + 1] + c[2 * k + 1] + d[2 * k + 1]) * ic;
    ow[k] = (uint32_t)f2bf(r0) | ((uint32_t)f2bf(r1) << 16);
  }
  ((uint4*)sout)[(size_t)node * 16 + q] = o;
}

__global__ void beta_kernel(const float* __restrict__ beta, float* __restrict__ betas) {
  if (threadIdx.x == 0) {
    float mx = beta[0];
    for (int i = 1; i < NLAYER + 1; ++i) mx = fmaxf(mx, beta[i]);
    float e[NLAYER + 1];
    float s = 0.f;
    for (int i = 0; i < NLAYER + 1; ++i) {
      e[i] = expf(beta[i] - mx);
      s += e[i];
    }
    const float inv = 1.f / s;
    for (int i = 0; i < NLAYER + 1; ++i) betas[i] = e[i] * inv;
  }
}

// W[K][N] f32 -> Wt[N][K] bf16
__global__ void wconv_kernel(const float* __restrict__ W, ushort* __restrict__ Wt,
                             int K, int Nn) {
  const size_t matoff = (size_t)blockIdx.z * K * Nn;
  const int o = blockIdx.x * 256 + threadIdx.x;
  if (o >= K * Nn) return;
  const int nn = o / K;
  const int kk = o - nn * K;
  Wt[matoff + o] = f2bf(W[matoff + (size_t)kk * Nn + nn]);
}

// U1 and U2 (both [L][256][256]) in one launch
__global__ void wconvU_kernel(const float* __restrict__ U1, const float* __restrict__ U2,
                              ushort* __restrict__ U1T, ushort* __restrict__ U2T) {
  const int li = blockIdx.z;
  const float* W = (li < NLAYER) ? U1 : U2;
  ushort* Wt = (li < NLAYER) ? U1T : U2T;
  const size_t matoff = (size_t)(li % NLAYER) * 256 * 256;
  const int o = blockIdx.x * 256 + threadIdx.x;
  const int nn = o >> 8;
  const int kk = o & 255;
  Wt[matoff + o] = f2bf(W[matoff + (size_t)kk * 256 + nn]);
}

// x f32 -> bf16, 8/thread
__global__ void xcast_kernel(const float* __restrict__ x, ushort* __restrict__ xb, int n8) {
  const int i = blockIdx.x * 256 + threadIdx.x;
  if (i >= n8) return;
  const f32x4 v0 = ((const f32x4*)x)[(size_t)i * 2];
  const f32x4 v1 = ((const f32x4*)x)[(size_t)i * 2 + 1];
  bf16x8 o;
#pragma unroll
  for (int q = 0; q < 4; ++q) {
    o[q] = (short)f2bf(v0[q]);
    o[q + 4] = (short)f2bf(v1[q]);
  }
  *(bf16x8*)(xb + (size_t)i * 8) = o;
}

// Win GEMM (z0): A bf16 [M x 128], B bf16 [256 x 128], C bf16 [M x 256].
__global__ __launch_bounds__(512, 4) void gemm_win(
    const ushort* __restrict__ A, const ushort* __restrict__ B,
    const float* __restrict__ bias, ushort* __restrict__ C, int M) {
  __shared__ ushort lA[128 * 64];
  __shared__ ushort lB[256 * 64];
  const int tid = threadIdx.x;
  const int m0 = blockIdx.x * 128;
  const int lane = tid & 63;
  const int w = tid >> 6;
  const int wm = (w >> 2) * 64;
  const int wn = (w & 3) * 64;
  const int rr = tid >> 3;       // 0..63
  const int cc = tid & 7;
  const int ccs = cc ^ (rr & 7);
  const bool full = (m0 + 128 <= M);
  f32x4 acc[4][4] = {};
  const int K = 128;

#pragma unroll
  for (int s = 0; s < 2; ++s) {
    const int k0 = s * 64;
    if (full) {
#pragma unroll
      for (int p = 0; p < 2; ++p) {
        const int row = p * 64 + rr;
        gll16(A + (size_t)(m0 + row) * K + k0 + ccs * 8,
              lA + (size_t)(p * 64 + w * 8) * 64);
      }
    } else {
#pragma unroll
      for (int p = 0; p < 2; ++p) {
        const int row = p * 64 + rr;
        const int gm = m0 + row;
        bf16x8 av = {0, 0, 0, 0, 0, 0, 0, 0};
        if (gm < M) av = *(const bf16x8*)(A + (size_t)gm * K + k0 + cc * 8);
        const uint32_t off = (uint32_t)((row * 128 + cc * 16) ^ ((row & 7) << 4));
        *(bf16x8*)((char*)lA + off) = av;
      }
    }
#pragma unroll
    for (int p = 0; p < 4; ++p) {
      const int row = p * 64 + rr;
      gll16(B + (size_t)row * K + k0 + ccs * 8,
            lB + (size_t)(p * 64 + w * 8) * 64);
    }
    __syncthreads();
#pragma unroll
    for (int kk = 0; kk < 2; ++kk) {
      bf16x8 ah[4];
#pragma unroll
      for (int i = 0; i < 4; ++i) {
        const int arow = wm + i * 16 + (lane & 15);
        const uint32_t ao =
            (uint32_t)((arow * 128 + kk * 64 + ((lane >> 4) * 16)) ^ ((arow & 7) << 4));
        ah[i] = *(const bf16x8*)((const char*)lA + ao);
      }
#pragma unroll
      for (int j = 0; j < 4; ++j) {
        const int brow = wn + j * 16 + (lane & 15);
        const uint32_t bo =
            (uint32_t)((brow * 128 + kk * 64 + ((lane >> 4) * 16)) ^ ((brow & 7) << 4));
        const bf16x8 bv = *(const bf16x8*)((const char*)lB + bo);
#pragma unroll
        for (int i = 0; i < 4; ++i)
          acc[i][j] = __builtin_amdgcn_mfma_f32_16x16x32_bf16(ah[i], bv, acc[i][j], 0, 0, 0);
      }
    }
    __syncthreads();
  }
  float bi[4];
#pragma unroll
  for (int j = 0; j < 4; ++j) bi[j] = bias[wn + j * 16 + (lane & 15)];
#pragma unroll
  for (int i = 0; i < 4; ++i) {
    const int gm0 = m0 + wm + i * 16 + ((lane >> 4) << 2);
#pragma unroll
    for (int r = 0; r < 4; ++r) {
      const int gm = gm0 + r;
      if (gm < M) {
        const size_t base = (size_t)gm * 256 + wn + (lane & 15);
#pragma unroll
        for (int j = 0; j < 4; ++j)
          C[base + j * 16] = f2bf(acc[i][j][r] + bi[j]);
      }
    }
  }
}

// ---------------------------------------------------------------------------
extern "C" void kernel_launch(void* const* d_in, const int* in_sizes, int n_in,
                              void* d_out, int out_size, void* d_ws, size_t ws_size,
                              hipStream_t stream) {
  const float* x = (const float*)d_in[0];
  const int* eidx = (const int*)d_in[1];
  const float* Win = (const float*)d_in[2];
  const float* bin_ = (const float*)d_in[3];
  const float* W1 = (const float*)d_in[4];
  const float* b1 = (const float*)d_in[5];
  const float* W2 = (const float*)d_in[6];
  const float* b2 = (const float*)d_in[7];
  const float* U1 = (const float*)d_in[8];
  const float* c1 = (const float*)d_in[9];
  const float* U2 = (const float*)d_in[10];
  const float* c2 = (const float*)d_in[11];
  const float* ln_g = (const float*)d_in[12];
  const float* ln_b = (const float*)d_in[13];
  const float* beta = (const float*)d_in[14];
  float* outp = (float*)d_out;

  const int Nn = in_sizes[0] / 128;  // 50000
  const int E = in_sizes[1] / 2;     // 800000
  const int* srcv = eidx;
  const int* dstv = eidx + E;

  char* p = (char*)d_ws;
  auto alloc = [&](size_t bytes) {
    char* r = p;
    p += (bytes + 255) & ~(size_t)255;
    return r;
  };
  ushort* hbuf = (ushort*)alloc((size_t)Nn * HIDC * 2);  // h bf16
  ushort* TSO = (ushort*)alloc((size_t)Nn * HIDC * 2);   // T | s, later O
  ushort* xbf = (ushort*)alloc((size_t)Nn * 128 * 2);
  ushort* WinT = (ushort*)alloc(128 * 256 * 2);
  ushort* W1T = (ushort*)alloc((size_t)NLAYER * 256 * 128 * 2);
  ushort* W2T = (ushort*)alloc((size_t)NLAYER * 128 * 256 * 2);
  ushort* U1T = (ushort*)alloc((size_t)NLAYER * 256 * 256 * 2);
  ushort* U2T = (ushort*)alloc((size_t)NLAYER * 256 * 256 * 2);
  int* deg = (int*)alloc((size_t)Nn * 4);
  int* rowptr = (int*)alloc((size_t)(Nn + 1) * 4);
  int* fillptr = (int*)alloc((size_t)Nn * 4);
  float* invc = (float*)alloc((size_t)Nn * 4);
  int* colv = (int*)alloc((size_t)E * 4);
  int* excl = (int*)alloc((size_t)Nn * 4);
  int* bsum = (int*)alloc(256 * 4);
  int* boff = (int*)alloc(256 * 4);
  float* betas = (float*)alloc(64);

  // z-history slots: as many as fit (G in [2, 11])
  const size_t ZS = (size_t)Nn * HIDC;
  const size_t slotB = ZS * 2;
  const size_t used = (size_t)(p - (char*)d_ws);
  int G = 2;
  if (ws_size > used + 4096) {
    size_t fit = (ws_size - used - 4096) / (slotB + 256);
    G = (int)(fit < 2 ? 2 : (fit > NLAYER + 1 ? NLAYER + 1 : fit));
  }
  ushort* zbase = (ushort*)alloc((size_t)G * slotB);

  ushort* T128 = TSO;
  ushort* s128 = TSO + (size_t)Nn * MSGC;
  ushort* Obuf = TSO;  // reuses T|s after both consumed

  const int nscan = (Nn + 255) / 256;
  const int mb128 = (Nn + 127) / 128;
  const int mb64 = (Nn + 63) / 64;
  const int nagg = (Nn + 15) / 16;
  const int total8 = (Nn * HIDC) / 8;

  hipMemsetAsync(deg, 0, (size_t)Nn * 4, stream);
  count_kernel<<<(E + 255) / 256, 256, 0, stream>>>(dstv, deg, E);
  scanA_kernel<<<nscan, 256, 0, stream>>>(deg, excl, bsum, Nn);
  scanB_kernel<<<1, 256, 0, stream>>>(bsum, boff, nscan);
  scanC_kernel<<<nscan, 256, 0, stream>>>(deg, excl, boff, rowptr, fillptr, invc, Nn, E);
  fill_kernel<<<(E + 255) / 256, 256, 0, stream>>>(srcv, dstv, fillptr, colv, E);
  beta_kernel<<<1, 64, 0, stream>>>(beta, betas);
  xcast_kernel<<<(Nn * 16 + 255) / 256, 256, 0, stream>>>(x, xbf, Nn * 16);
  wconv_kernel<<<dim3(128, 1, 1), 256, 0, stream>>>(Win, WinT, 128, 256);
  wconv_kernel<<<dim3(128, 1, NLAYER), 256, 0, stream>>>(W1, W1T, 256, 128);
  wconv_kernel<<<dim3(128, 1, NLAYER), 256, 0, stream>>>(W2, W2T, 128, 256);
  wconvU_kernel<<<dim3(256, 1, 2 * NLAYER), 256, 0, stream>>>(U1, U2, U1T, U2T);

  // fold bookkeeping
  int pend = 0, l0 = 0;
  bool first = true;
  auto flush = [&]() {
    if (pend > 0) {
      if (first)
        fold_kernel<1><<<(total8 + 255) / 256, 256, 0, stream>>>(zbase, ZS, betas, l0,
                                                                 pend, outp, total8);
      else
        fold_kernel<0><<<(total8 + 255) / 256, 256, 0, stream>>>(zbase, ZS, betas, l0,
                                                                 pend, outp, total8);
      first = false;
      l0 += pend;
      pend = 0;
    }
  };

  // z0 = x @ Win + bin -> slot 0
  ushort* zcur = zbase;
  gemm_win<<<mb128, 512, 0, stream>>>(xbf, WinT, bin_, zcur, Nn);
  pend = 1;

  for (int l = 0; l < NLAYER; ++l) {
    // T = bf16(relu(z @ W1 + b1))
    gemm_w1_64<<<mb64, 256, 0, stream>>>(zcur, W1T + (size_t)l * 256 * 128,
                                         b1 + l * 128, T128, Nn);
    // s = bf16(segmean(T))
    agg128_kernel<<<nagg, 256, 0, stream>>>(T128, rowptr, colv, invc, s128, Nn);
    // h = bf16(z + s @ W2 + b2)
    gemm_big64<0, 1, 0><<<mb64, 256, 0, stream>>>(s128, W2T + (size_t)l * 128 * 256,
                                                  b2 + l * 256, zcur, hbuf, nullptr,
                                                  nullptr, Nn, 128);
    // O = bf16(relu(h @ U1 + c1))
    gemm_big64<1, 0, 0><<<mb64, 256, 0, stream>>>(hbuf, U1T + (size_t)l * 256 * 256,
                                                  c1 + l * 256, nullptr, Obuf, nullptr,
                                                  nullptr, Nn, 256);
    // fold if all slots full
    if (pend == G) flush();
    // z' = bf16(LN(O @ U2 + c2)*g + b)
    ushort* znext = zbase + (size_t)pend * ZS;
    gemm_big64<0, 0, 1><<<mb64, 256, 0, stream>>>(Obuf, U2T + (size_t)l * 256 * 256,
                                                  c2 + l * 256, nullptr, znext,
                                                  ln_g + l * 256, ln_b + l * 256, Nn, 256);
    zcur = znext;
    pend++;
  }
  flush();
}